// Round 9
// baseline (414.144 us; speedup 1.0000x reference)
//
#include <hip/hip_runtime.h>

// GraphSAGE 2-layer forward on MI355X.
// Round 19: delete the bin-sort. r18 post-mortem: unified t2 was neutral --
// TCC granularity is 64B sectors and both layouts cost 2 sectors/edge; agg
// kernels are bracketed at ~2.6 TB/s random-sector service (3 structures x
// 3 layouts all ~273-280us). Remaining fat: the CSR chain. scatter_det +
// bin_fill move 25MB of packed[] and run 4.8M LDS lane-atomics (~3-4cy each,
// r13) solely to make csr_src node-contiguous -- but neighbor ORDER within a
// node is irrelevant to a mean. Now: deg via direct global atomics (L2-
// resident 400KB), scan1/scan2 -> row_start, and scatter_direct writes
// csr_src[atomicAdd(cursor[dst])] = src. packed/scatter_det/bin_fill gone.
// Neighbor order = atomic order (FP reorder ~1e-6 << 0.078 absmax).
//   agg kernels + gemm12: r18 form (wave=2 nodes, 16-edge window, 8 uint2
//   gathers/lane in flight, zero-row predication; unified 128B-stride t2).

typedef __attribute__((ext_vector_type(8))) short bf16x8;
typedef __attribute__((ext_vector_type(4))) float f32x4;
typedef __attribute__((ext_vector_type(2))) float f32x2;

#define NB 256                 // deg-count blocks

#define OFF_ROWSTART (1ull << 20)   // 400 KB
#define OFF_DEG      (2ull << 20)   // 400 KB  per-node degree
#define OFF_SCAN     (3ull << 20)   // 400 KB  block-local exclusive prefix
#define OFF_BSUMS    (4ull << 20)
#define OFF_BOFFS    ((4ull << 20) + (64ull << 10))
#define OFF_CURSOR   (5ull << 20)   // 400 KB  scatter cursors
#define OFF_CSR      (12ull << 20)  // 6.4 MB
#define OFF_W1T      (19ull << 20)  // 64 KB
#define OFF_W2T      (20ull << 20)  // 20 KB
#define OFF_XB       (21ull << 20)  // 25.6 MB bf16 (gemm12 self-term)
#define OFF_XQ       (47ull << 20)  // 12.8 MB + zero row (fp8, N+1 rows)
#define OFF_AGGB     (61ull << 20)  // 25.6 MB bf16
#define OFF_T2       (87ull << 20)  // 12.8 MB + zero row (64-short rows, 80B used)

static __device__ __forceinline__ unsigned short f2b(float f) {
    unsigned int u = __float_as_uint(f);
    u += 0x7fffu + ((u >> 16) & 1u);   // round-to-nearest-even
    return (unsigned short)(u >> 16);
}
static __device__ __forceinline__ float blo(unsigned int v) { return __uint_as_float(v << 16); }
static __device__ __forceinline__ float bhi(unsigned int v) { return __uint_as_float(v & 0xffff0000u); }

// --------------------------------------- merged prep: cast + degree count
// blocks [0, castBlocks): x -> xb (bf16) + xq (fp8 e4m3), 16 dims/thread.
// next 128: W1t transpose; next 80: W2t; next 1: zero rows.
// blocks [castPlus, castPlus+NB): deg[dst[e]]++ via global atomics.

__global__ __launch_bounds__(256) void cast_deg(
    const float* __restrict__ x,
    const float* __restrict__ W1s, const float* __restrict__ W1n,
    const float* __restrict__ W2s, const float* __restrict__ W2n,
    unsigned short* __restrict__ xb, unsigned char* __restrict__ xq,
    unsigned short* __restrict__ W1t, unsigned short* __restrict__ W2t,
    unsigned short* __restrict__ t2,
    const int* __restrict__ dst, int* __restrict__ deg,
    int n16, int castBlocks, int castPlus, int N, int E) {
    int blk = blockIdx.x, t = threadIdx.x;
    if (blk >= castPlus) {
        int b = blk - castPlus;
        int chunk = (E + NB - 1) / NB;
        int base = b * chunk;
        int lim = min(base + chunk, E);
        for (int e = base + t; e < lim; e += 256)
            atomicAdd(&deg[dst[e]], 1);
        return;
    }
    if (blk < castBlocks) {
        int i = blk * 256 + t;
        if (i >= n16) return;
        const float4* p = (const float4*)x + (size_t)i * 4;
        float4 v0 = p[0], v1 = p[1], v2 = p[2], v3 = p[3];
        float f[16] = {v0.x, v0.y, v0.z, v0.w, v1.x, v1.y, v1.z, v1.w,
                       v2.x, v2.y, v2.z, v2.w, v3.x, v3.y, v3.z, v3.w};
        unsigned short ob[16];
#pragma unroll
        for (int k = 0; k < 16; k++) ob[k] = f2b(f[k]);
        *(float4*)(xb + (size_t)i * 16) = *(float4*)&ob[0];
        *(float4*)(xb + (size_t)i * 16 + 8) = *(float4*)&ob[8];
        unsigned int w[4];
#pragma unroll
        for (int k = 0; k < 4; k++) {
            int u = __builtin_amdgcn_cvt_pk_fp8_f32(f[4 * k + 0], f[4 * k + 1], 0, false);
            u = __builtin_amdgcn_cvt_pk_fp8_f32(f[4 * k + 2], f[4 * k + 3], u, true);
            w[k] = (unsigned int)u;
        }
        *(uint4*)(xq + (size_t)i * 16) = *(uint4*)w;
    } else if (blk < castBlocks + 128) {
        int c = blk - castBlocks;
        float v = (t < 128) ? W1s[(size_t)t * 128 + c] : W1n[(size_t)(t - 128) * 128 + c];
        W1t[(size_t)c * 256 + t] = f2b(v);
    } else if (blk < castBlocks + 208) {
        if (t < 128) {
            int c = blk - castBlocks - 128;
            float v = (c < 40) ? W2s[(size_t)t * 40 + c] : W2n[(size_t)t * 40 + (c - 40)];
            W2t[(size_t)c * 128 + t] = f2b(v);
        }
    } else {
        // zero rows at index N (xq: 128 B; t2: 128 B)
        if (t < 32) ((unsigned int*)(xq + (size_t)N * 128))[t] = 0u;
        else if (t < 64) ((unsigned int*)(t2 + (size_t)N * 64))[t - 32] = 0u;
    }
}

// ------------------------------------------------------ direct CSR build

__global__ void scan1(const int* __restrict__ in, int* __restrict__ tmp,
                      int* __restrict__ bsums, int M) {
    __shared__ int s[256];
    int t = threadIdx.x;
    int i = blockIdx.x * 256 + t;
    int v = (i < M) ? in[i] : 0;
    s[t] = v;
    __syncthreads();
    for (int off = 1; off < 256; off <<= 1) {
        int u = (t >= off) ? s[t - off] : 0;
        __syncthreads();
        s[t] += u;
        __syncthreads();
    }
    if (i < M) tmp[i] = s[t] - v;
    if (t == 255) bsums[blockIdx.x] = s[t];
}

__global__ void scan2(const int* __restrict__ bsums, int* __restrict__ boffs, int nb) {
    __shared__ int s[1024];
    int t = threadIdx.x;
    int v = (t < nb) ? bsums[t] : 0;
    s[t] = v;
    __syncthreads();
    for (int off = 1; off < 1024; off <<= 1) {
        int u = (t >= off) ? s[t - off] : 0;
        __syncthreads();
        s[t] += u;
        __syncthreads();
    }
    if (t < nb) boffs[t] = s[t] - v;
}

// row_start[i] = blockwise-exclusive + block offset; cursor = copy for scatter.
__global__ void finish_rs(const int* __restrict__ tmp, const int* __restrict__ boffs,
                          int* __restrict__ row_start, int* __restrict__ cursor,
                          int N, int E) {
    int i = blockIdx.x * 256 + threadIdx.x;
    if (i < N) {
        int v = tmp[i] + boffs[i >> 8];
        row_start[i] = v;
        cursor[i] = v;
    }
    if (i == N) row_start[N] = E;
}

__global__ __launch_bounds__(256) void scatter_direct(
    const int* __restrict__ src, const int* __restrict__ dst,
    int* __restrict__ cursor, int* __restrict__ csr_src, int E) {
    int stride = gridDim.x * 256;
    for (int e = blockIdx.x * 256 + threadIdx.x; e < E; e += stride) {
        int d = dst[e];
        int pos = atomicAdd(&cursor[d], 1);
        csr_src[pos] = src[e];
    }
}

// ------------------------------------------------------- aggregation kernels

// Wave = 2 nodes (32-lane half each). Within a half: group g (16 lanes)
// handles edges e+2k+g, k=0..7 -> 16-edge window per node, 8 gathers/lane
// in flight. Lane-in-group l owns dims [8l, 8l+8) of the 128B fp8 row via
// uint2. Out-of-range slots clamp to zero row N. Reduce = 1 shuffle stage.
__global__ void agg_mean_fp8(const unsigned char* __restrict__ xq,
                             const int* __restrict__ row_start,
                             const int* __restrict__ csr_src,
                             unsigned short* __restrict__ aggb, int N) {
    int wv = (blockIdx.x * blockDim.x + threadIdx.x) >> 6;
    int lane = threadIdx.x & 63;
    if (2 * wv >= N) return;
    int node = 2 * wv + (lane >> 5);
    bool valid = node < N;
    int hl = lane & 31;
    int g = hl >> 4;
    int l = hl & 15;
    int beg = valid ? row_start[node] : 0;
    int end = valid ? row_start[node + 1] : 0;
    const char* xbase = (const char*)xq;
    unsigned loff = (unsigned)l << 3;

    float a[8];
#pragma unroll
    for (int k = 0; k < 8; k++) a[k] = 0.f;

    for (int e = beg; e < end; e += 16) {
        int s[8];
#pragma unroll
        for (int k = 0; k < 8; k++) {
            int ee = e + 2 * k + g;
            int idx = csr_src[min(ee, end - 1)];
            s[k] = (ee < end) ? idx : N;          // N = zero row
        }
#pragma unroll
        for (int k = 0; k < 8; k++) {
            uint2 v = *(const uint2*)(xbase + (((unsigned)s[k] << 7) + loff));
            f32x2 p0 = __builtin_amdgcn_cvt_pk_f32_fp8(v.x, false);
            f32x2 p1 = __builtin_amdgcn_cvt_pk_f32_fp8(v.x, true);
            f32x2 p2 = __builtin_amdgcn_cvt_pk_f32_fp8(v.y, false);
            f32x2 p3 = __builtin_amdgcn_cvt_pk_f32_fp8(v.y, true);
            a[0] += p0.x; a[1] += p0.y; a[2] += p1.x; a[3] += p1.y;
            a[4] += p2.x; a[5] += p2.y; a[6] += p3.x; a[7] += p3.y;
        }
    }

#pragma unroll
    for (int k = 0; k < 8; k++)
        a[k] += __shfl_xor(a[k], 16);          // combine the 2 groups
    if (g == 0 && valid) {
        float inv = 1.0f / fmaxf((float)(end - beg), 1.0f);
        unsigned int ow[4];
#pragma unroll
        for (int k = 0; k < 4; k++)
            ow[k] = (unsigned int)f2b(a[2 * k] * inv) |
                    ((unsigned int)f2b(a[2 * k + 1] * inv) << 16);
        *(uint4*)((char*)aggb + (((unsigned)node << 8) + ((unsigned)l << 4))) = *(uint4*)ow;
    }
}

// Same 2-node/16-edge-window structure over UNIFIED t2 (128B-stride rows,
// 80B used). Lanes l 0-9 of a group read uint2 at row*128 + 8l -- single
// base, branchless. Lanes 10-15 idle. 8 gathers/lane in flight.
__global__ void agg2_add(const unsigned short* __restrict__ t2,
                         const int* __restrict__ row_start,
                         const int* __restrict__ csr_src, const float* __restrict__ b2,
                         float* __restrict__ out, int N) {
    int wv = (blockIdx.x * blockDim.x + threadIdx.x) >> 6;
    int lane = threadIdx.x & 63;
    if (2 * wv >= N) return;
    int node = 2 * wv + (lane >> 5);
    bool valid = node < N;
    int hl = lane & 31;
    int g = hl >> 4;
    int l = hl & 15;
    int beg = valid ? row_start[node] : 0;
    int end = valid ? row_start[node + 1] : 0;
    const char* tb = (const char*)t2;
    bool active = (l < 10);
    unsigned loff = (unsigned)l << 3;

    float a0 = 0.f, a1 = 0.f, a2 = 0.f, a3 = 0.f;

    for (int e = beg; e < end; e += 16) {
        int s[8];
#pragma unroll
        for (int k = 0; k < 8; k++) {
            int ee = e + 2 * k + g;
            int idx = csr_src[min(ee, end - 1)];
            s[k] = (ee < end) ? idx : N;          // N = zero row
        }
        if (active) {
#pragma unroll
            for (int k = 0; k < 8; k++) {
                uint2 v = *(const uint2*)(tb + (((unsigned)s[k] << 7) + loff));
                a0 += blo(v.x); a1 += bhi(v.x);
                a2 += blo(v.y); a3 += bhi(v.y);
            }
        }
    }

    a0 += __shfl_xor(a0, 16);
    a1 += __shfl_xor(a1, 16);
    a2 += __shfl_xor(a2, 16);
    a3 += __shfl_xor(a3, 16);
    if (g == 0 && active && valid) {
        float inv = 1.0f / fmaxf((float)(end - beg), 1.0f);
        float4 bb = ((const float4*)b2)[l];
        float4* op = (float4*)((char*)out + ((unsigned)node * 160u + ((unsigned)l << 4)));
        float4 cur = *op;
        cur.x += a0 * inv + bb.x;
        cur.y += a1 * inv + bb.y;
        cur.z += a2 * inv + bb.z;
        cur.w += a3 * inv + bb.w;
        *op = cur;
    }
}

// --------------------------------------------------------------- fused GEMM
// Phase 1: h1 = relu([xb|aggb] @ W1cat + b1) into LDS (128x136-stride bf16).
// Phase 2: [out_self | t2] = h1_tile @ W2cat (W2t in LDS, loaded once).

__global__ __launch_bounds__(256) void gemm12_mfma(
    const unsigned short* __restrict__ xb, const unsigned short* __restrict__ aggb,
    const unsigned short* __restrict__ W1t, const unsigned short* __restrict__ W2t,
    const float* __restrict__ b1, float* __restrict__ out,
    unsigned short* __restrict__ t2, int N) {

    __shared__ unsigned short As[128 * 40];
    __shared__ unsigned short Bs[128 * 40];
    __shared__ unsigned short Hs[128 * 136];   // h1 tile, +8 pad
    __shared__ unsigned short B2[80 * 136];    // W2t resident

    int tid = threadIdx.x;
    int wave = tid >> 6, lane = tid & 63;
    int row0 = blockIdx.x * 128;
    int m = lane & 15, quad = lane >> 4;

    for (int idx = tid; idx < 1280; idx += 256) {
        int r = idx >> 4, seg = idx & 15;
        *(float4*)&B2[r * 136 + seg * 8] = *(const float4*)(W2t + (size_t)r * 128 + seg * 8);
    }

    f32x4 acc[2][8];
#pragma unroll
    for (int i = 0; i < 2; i++)
#pragma unroll
        for (int j = 0; j < 8; j++) acc[i][j] = (f32x4){0.f, 0.f, 0.f, 0.f};

    for (int k0 = 0; k0 < 256; k0 += 32) {
        __syncthreads();
        {
            int r = tid >> 1, kk = (tid & 1) * 16;
            int row = row0 + r;
            float4 v0 = make_float4(0, 0, 0, 0), v1 = v0;
            if (row < N) {
                const unsigned short* s = (k0 < 128)
                    ? (xb + (size_t)row * 128 + k0 + kk)
                    : (aggb + (size_t)row * 128 + (k0 - 128) + kk);
                const float4* p = (const float4*)s;
                v0 = p[0]; v1 = p[1];
            }
            *(float4*)&As[r * 40 + kk] = v0;
            *(float4*)&As[r * 40 + kk + 8] = v1;
            const float4* q2 = (const float4*)(W1t + (size_t)r * 256 + k0 + kk);
            float4 w0 = q2[0], w1 = q2[1];
            *(float4*)&Bs[r * 40 + kk] = w0;
            *(float4*)&Bs[r * 40 + kk + 8] = w1;
        }
        __syncthreads();

        bf16x8 af0 = *(bf16x8*)&As[(wave * 32 + m) * 40 + quad * 8];
        bf16x8 af1 = *(bf16x8*)&As[(wave * 32 + 16 + m) * 40 + quad * 8];
#pragma unroll
        for (int j = 0; j < 8; j++) {
            bf16x8 bfg = *(bf16x8*)&Bs[(j * 16 + m) * 40 + quad * 8];
            acc[0][j] = __builtin_amdgcn_mfma_f32_16x16x32_bf16(af0, bfg, acc[0][j], 0, 0, 0);
            acc[1][j] = __builtin_amdgcn_mfma_f32_16x16x32_bf16(af1, bfg, acc[1][j], 0, 0, 0);
        }
    }

#pragma unroll
    for (int j = 0; j < 8; j++) {
        int col = j * 16 + m;
        float bias = b1[col];
#pragma unroll
        for (int i = 0; i < 2; i++) {
#pragma unroll
            for (int r = 0; r < 4; r++) {
                int rl = wave * 32 + i * 16 + quad * 4 + r;
                Hs[rl * 136 + col] = f2b(fmaxf(acc[i][j][r] + bias, 0.f));
            }
        }
    }
    __syncthreads();

    f32x4 acc2[2][5];
#pragma unroll
    for (int i = 0; i < 2; i++)
#pragma unroll
        for (int j = 0; j < 5; j++) acc2[i][j] = (f32x4){0.f, 0.f, 0.f, 0.f};

#pragma unroll
    for (int k0 = 0; k0 < 128; k0 += 32) {
        bf16x8 af0 = *(bf16x8*)&Hs[(wave * 32 + m) * 136 + k0 + quad * 8];
        bf16x8 af1 = *(bf16x8*)&Hs[(wave * 32 + 16 + m) * 136 + k0 + quad * 8];
#pragma unroll
        for (int j = 0; j < 5; j++) {
            bf16x8 bfg = *(bf16x8*)&B2[(j * 16 + m) * 136 + k0 + quad * 8];
            acc2[0][j] = __builtin_amdgcn_mfma_f32_16x16x32_bf16(af0, bfg, acc2[0][j], 0, 0, 0);
            acc2[1][j] = __builtin_amdgcn_mfma_f32_16x16x32_bf16(af1, bfg, acc2[1][j], 0, 0, 0);
        }
    }

#pragma unroll
    for (int j = 0; j < 5; j++) {
        int col = j * 16 + m;
#pragma unroll
        for (int i = 0; i < 2; i++) {
#pragma unroll
            for (int r = 0; r < 4; r++) {
                int row = row0 + wave * 32 + i * 16 + quad * 4 + r;
                if (row < N) {
                    float v = acc2[i][j][r];
                    if (col < 40) {
                        out[(size_t)row * 40 + col] = v;
                    } else {
                        t2[(size_t)row * 64 + (col - 40)] = f2b(v);
                    }
                }
            }
        }
    }
}

// ------------------------------------------------------------------ launch

extern "C" void kernel_launch(void* const* d_in, const int* in_sizes, int n_in,
                              void* d_out, int out_size, void* d_ws, size_t ws_size,
                              hipStream_t stream) {
    const float* x   = (const float*)d_in[0];
    const int*   src = (const int*)d_in[1];
    const int*   dst = (const int*)d_in[2];
    const float* W1s = (const float*)d_in[3];
    const float* W1n = (const float*)d_in[4];
    const float* b1  = (const float*)d_in[5];
    const float* W2s = (const float*)d_in[6];
    const float* W2n = (const float*)d_in[7];
    const float* b2  = (const float*)d_in[8];
    float* out = (float*)d_out;

    int N = in_sizes[0] / 128;
    int E = in_sizes[1];

    char* ws = (char*)d_ws;
    int*            row_start  = (int*)(ws + OFF_ROWSTART);
    int*            deg        = (int*)(ws + OFF_DEG);
    int*            scanned    = (int*)(ws + OFF_SCAN);
    int*            bsums      = (int*)(ws + OFF_BSUMS);
    int*            boffs      = (int*)(ws + OFF_BOFFS);
    int*            cursor     = (int*)(ws + OFF_CURSOR);
    int*            csr_src    = (int*)(ws + OFF_CSR);
    unsigned short* W1t        = (unsigned short*)(ws + OFF_W1T);
    unsigned short* W2t        = (unsigned short*)(ws + OFF_W2T);
    unsigned short* xb         = (unsigned short*)(ws + OFF_XB);
    unsigned char*  xq         = (unsigned char*)(ws + OFF_XQ);
    unsigned short* aggb       = (unsigned short*)(ws + OFF_AGGB);
    unsigned short* t2         = (unsigned short*)(ws + OFF_T2);

    int n16 = N * 128 / 16;
    int castBlocks = (n16 + 255) / 256;
    int castPlus = castBlocks + 128 + 80 + 1;
    int scanBlocks = (N + 255) / 256;            // 391 for N=100000

    hipMemsetAsync(deg, 0, (size_t)(N + 1) * sizeof(int), stream);

    cast_deg<<<castPlus + NB, 256, 0, stream>>>(
        x, W1s, W1n, W2s, W2n, xb, xq, W1t, W2t, t2,
        dst, deg, n16, castBlocks, castPlus, N, E);
    scan1<<<scanBlocks, 256, 0, stream>>>(deg, scanned, bsums, N);
    scan2<<<1, 1024, 0, stream>>>(bsums, boffs, scanBlocks);
    finish_rs<<<scanBlocks + 1, 256, 0, stream>>>(scanned, boffs, row_start, cursor, N, E);
    scatter_direct<<<2048, 256, 0, stream>>>(src, dst, cursor, csr_src, E);

    int nodePairs = (N + 1) / 2;
    int aggBlocks = (nodePairs * 64 + 255) / 256;
    agg_mean_fp8<<<aggBlocks, 256, 0, stream>>>(xq, row_start, csr_src, aggb, N);
    gemm12_mfma<<<(N + 127) / 128, 256, 0, stream>>>(xb, aggb, W1t, W2t, b1, out, t2, N);
    agg2_add<<<aggBlocks, 256, 0, stream>>>(t2, row_start, csr_src, b2, out, N);
}

// Round 10
// 341.832 us; speedup vs baseline: 1.2115x; 1.2115x over previous
//
#include <hip/hip_runtime.h>

// GraphSAGE 2-layer forward on MI355X.
// Round 20: r15 base (verified 273.5us best) + single-pass bin_fill.
// r19 post-mortem: random 4B global writes amplify ~16x (WRITE 107MB for a
// 6.4MB csr; 64B sector writebacks + cross-XCD dirty sharing) -> the bin-
// structured scatter_det is the write-coalescing solution, keep it.
// r19 DID validate: (a) deg via global atomics + scan -> correct row_start;
// (b) nondeterministic neighbor order passes absmax (0.078125 exactly).
// So: bin_fill_lite = single pass using precomputed row_start for per-node
// offsets (deletes 6.4MB packed re-read + 1.6M LDS atomics + 128-step
// prefix/bin). deg atomics folded into cast_hist's edge pass.
//   agg_mean / agg2 (split t2lo/t2hi) / gemm12: byte-for-byte r15.
//   (wave = 2 nodes, 16-edge window, 8 uint2 gathers/lane, zero-row pred.)

typedef __attribute__((ext_vector_type(8))) short bf16x8;
typedef __attribute__((ext_vector_type(4))) float f32x4;
typedef __attribute__((ext_vector_type(2))) float f32x2;

#define BIN_SHIFT 7
#define BIN_SIZE  128
#define NB        256          // scatter blocks (= scan block size!)

#define OFF_ROWSTART (1ull << 20)                 // 400 KB
#define OFF_SCAND    ((1ull << 20) + (512ull << 10)) // 400 KB deg prefix
#define OFF_HIST     (2ull << 20)                 // 800 KB hist[bin*NB + blk]
#define OFF_SCAN     (3ull << 20)                 // 800 KB hist prefix
#define OFF_BSUMS    (4ull << 20)
#define OFF_BOFFS    ((4ull << 20) + (64ull << 10))
#define OFF_BSUMS2   ((4ull << 20) + (128ull << 10))
#define OFF_BOFFS2   ((4ull << 20) + (192ull << 10))
#define OFF_DEG      ((4ull << 20) + (256ull << 10)) // 400 KB
#define OFF_PACKED   (5ull << 20)   // 6.4 MB
#define OFF_CSR      (12ull << 20)  // 6.4 MB
#define OFF_W1T      (19ull << 20)  // 64 KB
#define OFF_W2T      (20ull << 20)  // 20 KB
#define OFF_XB       (21ull << 20)  // 25.6 MB bf16 (gemm12 self-term)
#define OFF_XQ       (47ull << 20)  // 12.8 MB + zero row (fp8, N+1 rows)
#define OFF_AGGB     (61ull << 20)  // 25.6 MB bf16
#define OFF_T2LO     (87ull << 20)  // 6.4 MB + zero row (32 bf16/row)
#define OFF_T2HI     (94ull << 20)  // 1.6 MB + zero row (8 bf16/row)

static __device__ __forceinline__ unsigned short f2b(float f) {
    unsigned int u = __float_as_uint(f);
    u += 0x7fffu + ((u >> 16) & 1u);   // round-to-nearest-even
    return (unsigned short)(u >> 16);
}
static __device__ __forceinline__ float blo(unsigned int v) { return __uint_as_float(v << 16); }
static __device__ __forceinline__ float bhi(unsigned int v) { return __uint_as_float(v & 0xffff0000u); }

// ------------------------- merged prep: cast + bin-hist + per-node degree

__global__ __launch_bounds__(256) void cast_hist(
    const float* __restrict__ x,
    const float* __restrict__ W1s, const float* __restrict__ W1n,
    const float* __restrict__ W2s, const float* __restrict__ W2n,
    unsigned short* __restrict__ xb, unsigned char* __restrict__ xq,
    unsigned short* __restrict__ W1t, unsigned short* __restrict__ W2t,
    unsigned short* __restrict__ t2lo, unsigned short* __restrict__ t2hi,
    const int* __restrict__ dst, int* __restrict__ hist, int* __restrict__ deg,
    int n16, int castBlocks, int castPlus, int N, int E, int nbins) {
    __shared__ int h[1024];
    int blk = blockIdx.x, t = threadIdx.x;
    if (blk >= castPlus) {
        // ---- histogram + degree part
        int b = blk - castPlus;
        for (int i = t; i < nbins; i += 256) h[i] = 0;
        __syncthreads();
        int chunk = (E + NB - 1) / NB;
        int base = b * chunk;
        int lim = min(base + chunk, E);
        for (int e = base + t; e < lim; e += 256) {
            int d = dst[e];
            atomicAdd(&h[d >> BIN_SHIFT], 1);
            atomicAdd(&deg[d], 1);               // validated r19
        }
        __syncthreads();
        for (int i = t; i < nbins; i += 256)
            hist[i * NB + b] = h[i];
        return;
    }
    if (blk < castBlocks) {
        int i = blk * 256 + t;
        if (i >= n16) return;
        const float4* p = (const float4*)x + (size_t)i * 4;
        float4 v0 = p[0], v1 = p[1], v2 = p[2], v3 = p[3];
        float f[16] = {v0.x, v0.y, v0.z, v0.w, v1.x, v1.y, v1.z, v1.w,
                       v2.x, v2.y, v2.z, v2.w, v3.x, v3.y, v3.z, v3.w};
        unsigned short ob[16];
#pragma unroll
        for (int k = 0; k < 16; k++) ob[k] = f2b(f[k]);
        *(float4*)(xb + (size_t)i * 16) = *(float4*)&ob[0];
        *(float4*)(xb + (size_t)i * 16 + 8) = *(float4*)&ob[8];
        unsigned int w[4];
#pragma unroll
        for (int k = 0; k < 4; k++) {
            int u = __builtin_amdgcn_cvt_pk_fp8_f32(f[4 * k + 0], f[4 * k + 1], 0, false);
            u = __builtin_amdgcn_cvt_pk_fp8_f32(f[4 * k + 2], f[4 * k + 3], u, true);
            w[k] = (unsigned int)u;
        }
        *(uint4*)(xq + (size_t)i * 16) = *(uint4*)w;
    } else if (blk < castBlocks + 128) {
        int c = blk - castBlocks;
        float v = (t < 128) ? W1s[(size_t)t * 128 + c] : W1n[(size_t)(t - 128) * 128 + c];
        W1t[(size_t)c * 256 + t] = f2b(v);
    } else if (blk < castBlocks + 208) {
        if (t < 128) {
            int c = blk - castBlocks - 128;
            float v = (c < 40) ? W2s[(size_t)t * 40 + c] : W2n[(size_t)t * 40 + (c - 40)];
            W2t[(size_t)c * 128 + t] = f2b(v);
        }
    } else {
        // zero rows at index N
        if (t < 32) ((unsigned int*)(xq + (size_t)N * 128))[t] = 0u;
        else if (t < 48) ((unsigned int*)(t2lo + (size_t)N * 32))[t - 32] = 0u;
        else if (t < 52) ((unsigned int*)(t2hi + (size_t)N * 8))[t - 48] = 0u;
    }
}

// ------------------------------------------------- CSR via counting sort

__global__ void scan1(const int* __restrict__ in, int* __restrict__ tmp,
                      int* __restrict__ bsums, int M) {
    __shared__ int s[256];
    int t = threadIdx.x;
    int i = blockIdx.x * 256 + t;
    int v = (i < M) ? in[i] : 0;
    s[t] = v;
    __syncthreads();
    for (int off = 1; off < 256; off <<= 1) {
        int u = (t >= off) ? s[t - off] : 0;
        __syncthreads();
        s[t] += u;
        __syncthreads();
    }
    if (i < M) tmp[i] = s[t] - v;
    if (t == 255) bsums[blockIdx.x] = s[t];
}

// block 0: scan bsums1[nb1] -> boffs1; block 1: scan bsums2[nb2] -> boffs2
__global__ void scan2(const int* __restrict__ bsums1, int* __restrict__ boffs1, int nb1,
                      const int* __restrict__ bsums2, int* __restrict__ boffs2, int nb2) {
    __shared__ int s[1024];
    const int* in = (blockIdx.x == 0) ? bsums1 : bsums2;
    int* outp = (blockIdx.x == 0) ? boffs1 : boffs2;
    int nb = (blockIdx.x == 0) ? nb1 : nb2;
    int t = threadIdx.x;
    int v = (t < nb) ? in[t] : 0;
    s[t] = v;
    __syncthreads();
    for (int off = 1; off < 1024; off <<= 1) {
        int u = (t >= off) ? s[t - off] : 0;
        __syncthreads();
        s[t] += u;
        __syncthreads();
    }
    if (t < nb) outp[t] = s[t] - v;
}

__global__ void finish_rs(const int* __restrict__ scand, const int* __restrict__ boffs2,
                          int* __restrict__ row_start, int N, int E) {
    int i = blockIdx.x * 256 + threadIdx.x;
    if (i < N) row_start[i] = scand[i] + boffs2[i >> 8];
    if (i == N) row_start[N] = E;
}

__global__ __launch_bounds__(256) void scatter_det(
    const int* __restrict__ src, const int* __restrict__ dst,
    const int* __restrict__ tmp, const int* __restrict__ boffs,
    unsigned int* __restrict__ packed, int E, int nbins) {
    __shared__ int cur[1024];
    int b = blockIdx.x, t = threadIdx.x;
    for (int i = t; i < nbins; i += 256) cur[i] = tmp[i * NB + b] + boffs[i];
    __syncthreads();
    int chunk = (E + NB - 1) / NB;
    int base = b * chunk;
    int lim = min(base + chunk, E);
    for (int e = base + t; e < lim; e += 256) {
        int d = dst[e];
        int bin = d >> BIN_SHIFT;
        int pos = atomicAdd(&cur[bin], 1);   // LDS atomic
        packed[pos] = ((unsigned int)(d & (BIN_SIZE - 1)) << 20) | (unsigned int)src[e];
    }
}

// Single pass: per-node offsets come from precomputed row_start.
// Neighbor order within a node = atomic arrival order (validated harmless).
__global__ __launch_bounds__(256) void bin_fill_lite(
    const unsigned int* __restrict__ packed, const int* __restrict__ row_start,
    int* __restrict__ csr_src, int N, int nbins, int E) {
    __shared__ int rs[BIN_SIZE];
    __shared__ int cnt[BIN_SIZE];
    int b = blockIdx.x;
    int t = threadIdx.x;
    int node0 = b << BIN_SHIFT;
    if (t < BIN_SIZE) {
        int node = node0 + t;
        rs[t] = row_start[min(node, N)];
        cnt[t] = 0;
    }
    __syncthreads();
    int beg = rs[0];
    int end = (b + 1 < nbins) ? row_start[min(node0 + BIN_SIZE, N)] : E;
    for (int i = beg + t; i < end; i += 256) {
        unsigned int p = packed[i];
        int dl = p >> 20;
        int s = p & 0xFFFFF;
        int ofs = atomicAdd(&cnt[dl], 1);
        csr_src[rs[dl] + ofs] = s;
    }
}

// ------------------------------------------------------- aggregation kernels

// Wave = 2 nodes (32-lane half each). Within a half: group g (16 lanes)
// handles edges e+2k+g, k=0..7 -> 16-edge window per node, 8 gathers/lane
// in flight. Lane-in-group l owns dims [8l, 8l+8) of the 128B fp8 row via
// uint2. Out-of-range slots clamp to zero row N. Reduce = 1 shuffle stage.
__global__ void agg_mean_fp8(const unsigned char* __restrict__ xq,
                             const int* __restrict__ row_start,
                             const int* __restrict__ csr_src,
                             unsigned short* __restrict__ aggb, int N) {
    int wv = (blockIdx.x * blockDim.x + threadIdx.x) >> 6;
    int lane = threadIdx.x & 63;
    if (2 * wv >= N) return;
    int node = 2 * wv + (lane >> 5);
    bool valid = node < N;
    int hl = lane & 31;
    int g = hl >> 4;
    int l = hl & 15;
    int beg = valid ? row_start[node] : 0;
    int end = valid ? row_start[node + 1] : 0;
    const char* xbase = (const char*)xq;
    unsigned loff = (unsigned)l << 3;

    float a[8];
#pragma unroll
    for (int k = 0; k < 8; k++) a[k] = 0.f;

    for (int e = beg; e < end; e += 16) {
        int s[8];
#pragma unroll
        for (int k = 0; k < 8; k++) {
            int ee = e + 2 * k + g;
            int idx = csr_src[min(ee, end - 1)];
            s[k] = (ee < end) ? idx : N;          // N = zero row
        }
#pragma unroll
        for (int k = 0; k < 8; k++) {
            uint2 v = *(const uint2*)(xbase + (((unsigned)s[k] << 7) + loff));
            f32x2 p0 = __builtin_amdgcn_cvt_pk_f32_fp8(v.x, false);
            f32x2 p1 = __builtin_amdgcn_cvt_pk_f32_fp8(v.x, true);
            f32x2 p2 = __builtin_amdgcn_cvt_pk_f32_fp8(v.y, false);
            f32x2 p3 = __builtin_amdgcn_cvt_pk_f32_fp8(v.y, true);
            a[0] += p0.x; a[1] += p0.y; a[2] += p1.x; a[3] += p1.y;
            a[4] += p2.x; a[5] += p2.y; a[6] += p3.x; a[7] += p3.y;
        }
    }

#pragma unroll
    for (int k = 0; k < 8; k++)
        a[k] += __shfl_xor(a[k], 16);          // combine the 2 groups
    if (g == 0 && valid) {
        float inv = 1.0f / fmaxf((float)(end - beg), 1.0f);
        unsigned int ow[4];
#pragma unroll
        for (int k = 0; k < 4; k++)
            ow[k] = (unsigned int)f2b(a[2 * k] * inv) |
                    ((unsigned int)f2b(a[2 * k + 1] * inv) << 16);
        *(uint4*)((char*)aggb + (((unsigned)node << 8) + ((unsigned)l << 4))) = *(uint4*)ow;
    }
}

// Same 2-node/16-edge-window structure over split bf16 t2. Lanes l 0-7 of a
// group read uint2 from t2lo (64B rows), 8-9 from t2hi (16B rows); l 10-15
// idle. 8 gathers/lane in flight. Zero rows at N keep the loop predicated.
__global__ void agg2_add(const unsigned short* __restrict__ t2lo,
                         const unsigned short* __restrict__ t2hi,
                         const int* __restrict__ row_start,
                         const int* __restrict__ csr_src, const float* __restrict__ b2,
                         float* __restrict__ out, int N) {
    int wv = (blockIdx.x * blockDim.x + threadIdx.x) >> 6;
    int lane = threadIdx.x & 63;
    if (2 * wv >= N) return;
    int node = 2 * wv + (lane >> 5);
    bool valid = node < N;
    int hl = lane & 31;
    int g = hl >> 4;
    int l = hl & 15;
    int beg = valid ? row_start[node] : 0;
    int end = valid ? row_start[node + 1] : 0;
    const char* lob = (const char*)t2lo;
    const char* hib = (const char*)t2hi;
    bool isLo = (l < 8);
    bool active = (l < 10);
    unsigned loff = isLo ? ((unsigned)l << 3) : ((unsigned)(l - 8) << 3);

    float a0 = 0.f, a1 = 0.f, a2 = 0.f, a3 = 0.f;

    for (int e = beg; e < end; e += 16) {
        int s[8];
#pragma unroll
        for (int k = 0; k < 8; k++) {
            int ee = e + 2 * k + g;
            int idx = csr_src[min(ee, end - 1)];
            s[k] = (ee < end) ? idx : N;          // N = zero row
        }
        if (active) {
#pragma unroll
            for (int k = 0; k < 8; k++) {
                uint2 v = isLo ? *(const uint2*)(lob + (((unsigned)s[k] << 6) + loff))
                               : *(const uint2*)(hib + (((unsigned)s[k] << 4) + loff));
                a0 += blo(v.x); a1 += bhi(v.x);
                a2 += blo(v.y); a3 += bhi(v.y);
            }
        }
    }

    a0 += __shfl_xor(a0, 16);
    a1 += __shfl_xor(a1, 16);
    a2 += __shfl_xor(a2, 16);
    a3 += __shfl_xor(a3, 16);
    if (g == 0 && active && valid) {
        float inv = 1.0f / fmaxf((float)(end - beg), 1.0f);
        float4 bb = ((const float4*)b2)[l];
        float4* op = (float4*)((char*)out + ((unsigned)node * 160u + ((unsigned)l << 4)));
        float4 cur = *op;
        cur.x += a0 * inv + bb.x;
        cur.y += a1 * inv + bb.y;
        cur.z += a2 * inv + bb.z;
        cur.w += a3 * inv + bb.w;
        *op = cur;
    }
}

// --------------------------------------------------------------- fused GEMM
// Phase 1: h1 = relu([xb|aggb] @ W1cat + b1) into LDS (128x136-stride bf16).
// Phase 2: [out_self | t2lo|t2hi] = h1_tile @ W2cat (W2t in LDS, loaded once).

__global__ __launch_bounds__(256) void gemm12_mfma(
    const unsigned short* __restrict__ xb, const unsigned short* __restrict__ aggb,
    const unsigned short* __restrict__ W1t, const unsigned short* __restrict__ W2t,
    const float* __restrict__ b1, float* __restrict__ out,
    unsigned short* __restrict__ t2lo, unsigned short* __restrict__ t2hi, int N) {

    __shared__ unsigned short As[128 * 40];
    __shared__ unsigned short Bs[128 * 40];
    __shared__ unsigned short Hs[128 * 136];   // h1 tile, +8 pad
    __shared__ unsigned short B2[80 * 136];    // W2t resident

    int tid = threadIdx.x;
    int wave = tid >> 6, lane = tid & 63;
    int row0 = blockIdx.x * 128;
    int m = lane & 15, quad = lane >> 4;

    for (int idx = tid; idx < 1280; idx += 256) {
        int r = idx >> 4, seg = idx & 15;
        *(float4*)&B2[r * 136 + seg * 8] = *(const float4*)(W2t + (size_t)r * 128 + seg * 8);
    }

    f32x4 acc[2][8];
#pragma unroll
    for (int i = 0; i < 2; i++)
#pragma unroll
        for (int j = 0; j < 8; j++) acc[i][j] = (f32x4){0.f, 0.f, 0.f, 0.f};

    for (int k0 = 0; k0 < 256; k0 += 32) {
        __syncthreads();
        {
            int r = tid >> 1, kk = (tid & 1) * 16;
            int row = row0 + r;
            float4 v0 = make_float4(0, 0, 0, 0), v1 = v0;
            if (row < N) {
                const unsigned short* s = (k0 < 128)
                    ? (xb + (size_t)row * 128 + k0 + kk)
                    : (aggb + (size_t)row * 128 + (k0 - 128) + kk);
                const float4* p = (const float4*)s;
                v0 = p[0]; v1 = p[1];
            }
            *(float4*)&As[r * 40 + kk] = v0;
            *(float4*)&As[r * 40 + kk + 8] = v1;
            const float4* q2 = (const float4*)(W1t + (size_t)r * 256 + k0 + kk);
            float4 w0 = q2[0], w1 = q2[1];
            *(float4*)&Bs[r * 40 + kk] = w0;
            *(float4*)&Bs[r * 40 + kk + 8] = w1;
        }
        __syncthreads();

        bf16x8 af0 = *(bf16x8*)&As[(wave * 32 + m) * 40 + quad * 8];
        bf16x8 af1 = *(bf16x8*)&As[(wave * 32 + 16 + m) * 40 + quad * 8];
#pragma unroll
        for (int j = 0; j < 8; j++) {
            bf16x8 bfg = *(bf16x8*)&Bs[(j * 16 + m) * 40 + quad * 8];
            acc[0][j] = __builtin_amdgcn_mfma_f32_16x16x32_bf16(af0, bfg, acc[0][j], 0, 0, 0);
            acc[1][j] = __builtin_amdgcn_mfma_f32_16x16x32_bf16(af1, bfg, acc[1][j], 0, 0, 0);
        }
    }

#pragma unroll
    for (int j = 0; j < 8; j++) {
        int col = j * 16 + m;
        float bias = b1[col];
#pragma unroll
        for (int i = 0; i < 2; i++) {
#pragma unroll
            for (int r = 0; r < 4; r++) {
                int rl = wave * 32 + i * 16 + quad * 4 + r;
                Hs[rl * 136 + col] = f2b(fmaxf(acc[i][j][r] + bias, 0.f));
            }
        }
    }
    __syncthreads();

    f32x4 acc2[2][5];
#pragma unroll
    for (int i = 0; i < 2; i++)
#pragma unroll
        for (int j = 0; j < 5; j++) acc2[i][j] = (f32x4){0.f, 0.f, 0.f, 0.f};

#pragma unroll
    for (int k0 = 0; k0 < 128; k0 += 32) {
        bf16x8 af0 = *(bf16x8*)&Hs[(wave * 32 + m) * 136 + k0 + quad * 8];
        bf16x8 af1 = *(bf16x8*)&Hs[(wave * 32 + 16 + m) * 136 + k0 + quad * 8];
#pragma unroll
        for (int j = 0; j < 5; j++) {
            bf16x8 bfg = *(bf16x8*)&B2[(j * 16 + m) * 136 + k0 + quad * 8];
            acc2[0][j] = __builtin_amdgcn_mfma_f32_16x16x32_bf16(af0, bfg, acc2[0][j], 0, 0, 0);
            acc2[1][j] = __builtin_amdgcn_mfma_f32_16x16x32_bf16(af1, bfg, acc2[1][j], 0, 0, 0);
        }
    }

#pragma unroll
    for (int j = 0; j < 5; j++) {
        int col = j * 16 + m;
#pragma unroll
        for (int i = 0; i < 2; i++) {
#pragma unroll
            for (int r = 0; r < 4; r++) {
                int row = row0 + wave * 32 + i * 16 + quad * 4 + r;
                if (row < N) {
                    float v = acc2[i][j][r];
                    if (col < 40) {
                        out[(size_t)row * 40 + col] = v;
                    } else {
                        int td = col - 40;
                        if (td < 32) t2lo[(size_t)row * 32 + td] = f2b(v);
                        else         t2hi[(size_t)row * 8 + (td - 32)] = f2b(v);
                    }
                }
            }
        }
    }
}

// ------------------------------------------------------------------ launch

extern "C" void kernel_launch(void* const* d_in, const int* in_sizes, int n_in,
                              void* d_out, int out_size, void* d_ws, size_t ws_size,
                              hipStream_t stream) {
    const float* x   = (const float*)d_in[0];
    const int*   src = (const int*)d_in[1];
    const int*   dst = (const int*)d_in[2];
    const float* W1s = (const float*)d_in[3];
    const float* W1n = (const float*)d_in[4];
    const float* b1  = (const float*)d_in[5];
    const float* W2s = (const float*)d_in[6];
    const float* W2n = (const float*)d_in[7];
    const float* b2  = (const float*)d_in[8];
    float* out = (float*)d_out;

    int N = in_sizes[0] / 128;
    int E = in_sizes[1];
    int nbins = (N + BIN_SIZE - 1) / BIN_SIZE;   // 782 for N=100000
    int M = nbins * NB;

    char* ws = (char*)d_ws;
    int*            row_start  = (int*)(ws + OFF_ROWSTART);
    int*            scand      = (int*)(ws + OFF_SCAND);
    int*            hist       = (int*)(ws + OFF_HIST);
    int*            scanned    = (int*)(ws + OFF_SCAN);
    int*            bsums      = (int*)(ws + OFF_BSUMS);
    int*            boffs      = (int*)(ws + OFF_BOFFS);
    int*            bsums2     = (int*)(ws + OFF_BSUMS2);
    int*            boffs2     = (int*)(ws + OFF_BOFFS2);
    int*            deg        = (int*)(ws + OFF_DEG);
    unsigned int*   packed     = (unsigned int*)(ws + OFF_PACKED);
    int*            csr_src    = (int*)(ws + OFF_CSR);
    unsigned short* W1t        = (unsigned short*)(ws + OFF_W1T);
    unsigned short* W2t        = (unsigned short*)(ws + OFF_W2T);
    unsigned short* xb         = (unsigned short*)(ws + OFF_XB);
    unsigned char*  xq         = (unsigned char*)(ws + OFF_XQ);
    unsigned short* aggb       = (unsigned short*)(ws + OFF_AGGB);
    unsigned short* t2lo       = (unsigned short*)(ws + OFF_T2LO);
    unsigned short* t2hi       = (unsigned short*)(ws + OFF_T2HI);

    int scanBlocksM = (M + 255) / 256;           // 782
    int scanBlocksN = (N + 255) / 256;           // 391

    int n16 = N * 128 / 16;
    int castBlocks = (n16 + 255) / 256;
    int castPlus = castBlocks + 128 + 80 + 1;

    hipMemsetAsync(deg, 0, (size_t)(N + 1) * sizeof(int), stream);

    cast_hist<<<castPlus + NB, 256, 0, stream>>>(
        x, W1s, W1n, W2s, W2n, xb, xq, W1t, W2t, t2lo, t2hi,
        dst, hist, deg, n16, castBlocks, castPlus, N, E, nbins);
    scan1<<<scanBlocksM, 256, 0, stream>>>(hist, scanned, bsums, M);
    scan1<<<scanBlocksN, 256, 0, stream>>>(deg, scand, bsums2, N);
    scan2<<<2, 1024, 0, stream>>>(bsums, boffs, scanBlocksM, bsums2, boffs2, scanBlocksN);
    finish_rs<<<scanBlocksN + 1, 256, 0, stream>>>(scand, boffs2, row_start, N, E);
    scatter_det<<<NB, 256, 0, stream>>>(src, dst, scanned, boffs, packed, E, nbins);
    bin_fill_lite<<<nbins, 256, 0, stream>>>(packed, row_start, csr_src, N, nbins, E);

    int nodePairs = (N + 1) / 2;
    int aggBlocks = (nodePairs * 64 + 255) / 256;
    agg_mean_fp8<<<aggBlocks, 256, 0, stream>>>(xq, row_start, csr_src, aggb, N);
    gemm12_mfma<<<(N + 127) / 128, 256, 0, stream>>>(xb, aggb, W1t, W2t, b1, out, t2lo, t2hi, N);
    agg2_add<<<aggBlocks, 256, 0, stream>>>(t2lo, t2hi, row_start, csr_src, b2, out, N);
}

// Round 11
// 274.246 us; speedup vs baseline: 1.5101x; 1.2464x over previous
//
#include <hip/hip_runtime.h>

// GraphSAGE 2-layer forward on MI355X.
// Round 21: FINAL — exact revert to r15, the verified optimum (273.5us).
// Falsified branches (counter evidence): r16 agg-into-GEMM fusion (occupancy
// starvation, 98.8us fused); r17 uint4 gathers (issue rate not binding);
// r18 unified t2 (64B-sector granularity -> neutral); r19 scatter_direct
// (random 4B global writes amplify ~16x: WRITE 107MB); r20 per-edge global
// deg atomics (same sector law: cast_hist +72us, WRITE 94MB).
// Surviving model: gather kernels pinned at ~2.6TB/s random-sector service
// (invariant across 4 structures x 3 layouts); counting-sort CSR is the
// write-coalescing optimum; GEMM ~30us with fused 2-layer epilogue.
//   agg_mean: fp8 rows 128B, wave=2 nodes, 16-edge window, 8 uint2
//             gathers/lane in flight, zero-row predication.
//   agg2:     same structure over split bf16 t2 (t2lo 64B / t2hi 16B rows).
//   prep:     cast + W transposes + bin-histogram merged in one launch.
// CSR: deterministic counting sort. GEMM: fused gemm12 (h1 tile in LDS).

typedef __attribute__((ext_vector_type(8))) short bf16x8;
typedef __attribute__((ext_vector_type(4))) float f32x4;
typedef __attribute__((ext_vector_type(2))) float f32x2;

#define BIN_SHIFT 7
#define BIN_SIZE  128
#define NB        256          // scatter blocks (= scan block size!)

#define OFF_ROWSTART (1ull << 20)   // 400 KB
#define OFF_HIST     (2ull << 20)   // 800 KB  hist[bin*NB + blk]
#define OFF_SCAN     (3ull << 20)   // 800 KB  block-local exclusive prefix
#define OFF_BSUMS    (4ull << 20)
#define OFF_BOFFS    ((4ull << 20) + (64ull << 10))
#define OFF_PACKED   (5ull << 20)   // 6.4 MB
#define OFF_CSR      (12ull << 20)  // 6.4 MB
#define OFF_W1T      (19ull << 20)  // 64 KB
#define OFF_W2T      (20ull << 20)  // 20 KB
#define OFF_XB       (21ull << 20)  // 25.6 MB bf16 (gemm12 self-term)
#define OFF_XQ       (47ull << 20)  // 12.8 MB + zero row (fp8, N+1 rows)
#define OFF_AGGB     (61ull << 20)  // 25.6 MB bf16
#define OFF_T2LO     (87ull << 20)  // 6.4 MB + zero row (32 bf16/row)
#define OFF_T2HI     (94ull << 20)  // 1.6 MB + zero row (8 bf16/row)

static __device__ __forceinline__ unsigned short f2b(float f) {
    unsigned int u = __float_as_uint(f);
    u += 0x7fffu + ((u >> 16) & 1u);   // round-to-nearest-even
    return (unsigned short)(u >> 16);
}
static __device__ __forceinline__ float blo(unsigned int v) { return __uint_as_float(v << 16); }
static __device__ __forceinline__ float bhi(unsigned int v) { return __uint_as_float(v & 0xffff0000u); }

// --------------------------------------- merged prep: cast_prep + hist_local
// blocks [0, castBlocks): x -> xb (bf16) + xq (fp8 e4m3), 16 dims/thread.
// next 128: W1t transpose; next 80: W2t; next 1: zero rows.
// blocks [castPlus, castPlus+NB): dst histogram into hist[bin*NB + blk].

__global__ __launch_bounds__(256) void cast_hist(
    const float* __restrict__ x,
    const float* __restrict__ W1s, const float* __restrict__ W1n,
    const float* __restrict__ W2s, const float* __restrict__ W2n,
    unsigned short* __restrict__ xb, unsigned char* __restrict__ xq,
    unsigned short* __restrict__ W1t, unsigned short* __restrict__ W2t,
    unsigned short* __restrict__ t2lo, unsigned short* __restrict__ t2hi,
    const int* __restrict__ dst, int* __restrict__ hist,
    int n16, int castBlocks, int castPlus, int N, int E, int nbins) {
    __shared__ int h[1024];
    int blk = blockIdx.x, t = threadIdx.x;
    if (blk >= castPlus) {
        // ---- histogram part
        int b = blk - castPlus;
        for (int i = t; i < nbins; i += 256) h[i] = 0;
        __syncthreads();
        int chunk = (E + NB - 1) / NB;
        int base = b * chunk;
        int lim = min(base + chunk, E);
        for (int e = base + t; e < lim; e += 256)
            atomicAdd(&h[dst[e] >> BIN_SHIFT], 1);
        __syncthreads();
        for (int i = t; i < nbins; i += 256)
            hist[i * NB + b] = h[i];
        return;
    }
    if (blk < castBlocks) {
        int i = blk * 256 + t;
        if (i >= n16) return;
        const float4* p = (const float4*)x + (size_t)i * 4;
        float4 v0 = p[0], v1 = p[1], v2 = p[2], v3 = p[3];
        float f[16] = {v0.x, v0.y, v0.z, v0.w, v1.x, v1.y, v1.z, v1.w,
                       v2.x, v2.y, v2.z, v2.w, v3.x, v3.y, v3.z, v3.w};
        unsigned short ob[16];
#pragma unroll
        for (int k = 0; k < 16; k++) ob[k] = f2b(f[k]);
        *(float4*)(xb + (size_t)i * 16) = *(float4*)&ob[0];
        *(float4*)(xb + (size_t)i * 16 + 8) = *(float4*)&ob[8];
        unsigned int w[4];
#pragma unroll
        for (int k = 0; k < 4; k++) {
            int u = __builtin_amdgcn_cvt_pk_fp8_f32(f[4 * k + 0], f[4 * k + 1], 0, false);
            u = __builtin_amdgcn_cvt_pk_fp8_f32(f[4 * k + 2], f[4 * k + 3], u, true);
            w[k] = (unsigned int)u;
        }
        *(uint4*)(xq + (size_t)i * 16) = *(uint4*)w;
    } else if (blk < castBlocks + 128) {
        int c = blk - castBlocks;
        float v = (t < 128) ? W1s[(size_t)t * 128 + c] : W1n[(size_t)(t - 128) * 128 + c];
        W1t[(size_t)c * 256 + t] = f2b(v);
    } else if (blk < castBlocks + 208) {
        if (t < 128) {
            int c = blk - castBlocks - 128;
            float v = (c < 40) ? W2s[(size_t)t * 40 + c] : W2n[(size_t)t * 40 + (c - 40)];
            W2t[(size_t)c * 128 + t] = f2b(v);
        }
    } else {
        // zero rows at index N
        if (t < 32) ((unsigned int*)(xq + (size_t)N * 128))[t] = 0u;
        else if (t < 48) ((unsigned int*)(t2lo + (size_t)N * 32))[t - 32] = 0u;
        else if (t < 52) ((unsigned int*)(t2hi + (size_t)N * 8))[t - 48] = 0u;
    }
}

// ------------------------------------------------- CSR via counting sort

__global__ void scan1(const int* __restrict__ in, int* __restrict__ tmp,
                      int* __restrict__ bsums, int M) {
    __shared__ int s[256];
    int t = threadIdx.x;
    int i = blockIdx.x * 256 + t;
    int v = (i < M) ? in[i] : 0;
    s[t] = v;
    __syncthreads();
    for (int off = 1; off < 256; off <<= 1) {
        int u = (t >= off) ? s[t - off] : 0;
        __syncthreads();
        s[t] += u;
        __syncthreads();
    }
    if (i < M) tmp[i] = s[t] - v;
    if (t == 255) bsums[blockIdx.x] = s[t];
}

__global__ void scan2(const int* __restrict__ bsums, int* __restrict__ boffs, int nb) {
    __shared__ int s[1024];
    int t = threadIdx.x;
    int v = (t < nb) ? bsums[t] : 0;
    s[t] = v;
    __syncthreads();
    for (int off = 1; off < 1024; off <<= 1) {
        int u = (t >= off) ? s[t - off] : 0;
        __syncthreads();
        s[t] += u;
        __syncthreads();
    }
    if (t < nb) boffs[t] = s[t] - v;
}

__global__ __launch_bounds__(256) void scatter_det(
    const int* __restrict__ src, const int* __restrict__ dst,
    const int* __restrict__ tmp, const int* __restrict__ boffs,
    unsigned int* __restrict__ packed, int E, int nbins) {
    __shared__ int cur[1024];
    int b = blockIdx.x, t = threadIdx.x;
    for (int i = t; i < nbins; i += 256) cur[i] = tmp[i * NB + b] + boffs[i];
    __syncthreads();
    int chunk = (E + NB - 1) / NB;
    int base = b * chunk;
    int lim = min(base + chunk, E);
    for (int e = base + t; e < lim; e += 256) {
        int d = dst[e];
        int bin = d >> BIN_SHIFT;
        int pos = atomicAdd(&cur[bin], 1);   // LDS atomic
        packed[pos] = ((unsigned int)(d & (BIN_SIZE - 1)) << 20) | (unsigned int)src[e];
    }
}

__global__ __launch_bounds__(256) void bin_fill(
    const unsigned int* __restrict__ packed, const int* __restrict__ tmp,
    const int* __restrict__ boffs,
    int* __restrict__ row_start, int* __restrict__ csr_src, int N, int nbins, int E) {
    __shared__ int cnt[BIN_SIZE];
    __shared__ int pre[BIN_SIZE];
    __shared__ int ex[BIN_SIZE];
    int b = blockIdx.x;
    int t = threadIdx.x;
    int node0 = b << BIN_SHIFT;
    int beg = tmp[b * NB] + boffs[b];
    int end = (b + 1 < nbins) ? (tmp[(b + 1) * NB] + boffs[b + 1]) : E;

    if (t < BIN_SIZE) cnt[t] = 0;
    __syncthreads();
    for (int i = beg + t; i < end; i += 256)
        atomicAdd(&cnt[packed[i] >> 20], 1);
    __syncthreads();
    if (t < BIN_SIZE) pre[t] = cnt[t];
    __syncthreads();
    for (int off = 1; off < BIN_SIZE; off <<= 1) {
        int u = (t < BIN_SIZE && t >= off) ? pre[t - off] : 0;
        __syncthreads();
        if (t < BIN_SIZE) pre[t] += u;
        __syncthreads();
    }
    if (t < BIN_SIZE) {
        ex[t] = pre[t] - cnt[t];
        int node = node0 + t;
        if (node < N) row_start[node] = beg + ex[t];
        cnt[t] = 0;
    }
    if (b == nbins - 1 && t == 0) row_start[N] = E;
    __syncthreads();
    for (int i = beg + t; i < end; i += 256) {
        unsigned int p = packed[i];
        int dl = p >> 20;
        int s = p & 0xFFFFF;
        int ofs = atomicAdd(&cnt[dl], 1);
        csr_src[beg + ex[dl] + ofs] = s;
    }
}

// ------------------------------------------------------- aggregation kernels

// Wave = 2 nodes (32-lane half each). Within a half: group g (16 lanes)
// handles edges e+2k+g, k=0..7 -> 16-edge window per node, 8 gathers/lane
// in flight. Lane-in-group l owns dims [8l, 8l+8) of the 128B fp8 row via
// uint2. Out-of-range slots clamp to zero row N. Reduce = 1 shuffle stage.
__global__ void agg_mean_fp8(const unsigned char* __restrict__ xq,
                             const int* __restrict__ row_start,
                             const int* __restrict__ csr_src,
                             unsigned short* __restrict__ aggb, int N) {
    int wv = (blockIdx.x * blockDim.x + threadIdx.x) >> 6;
    int lane = threadIdx.x & 63;
    if (2 * wv >= N) return;
    int node = 2 * wv + (lane >> 5);
    bool valid = node < N;
    int hl = lane & 31;
    int g = hl >> 4;
    int l = hl & 15;
    int beg = valid ? row_start[node] : 0;
    int end = valid ? row_start[node + 1] : 0;
    const char* xbase = (const char*)xq;
    unsigned loff = (unsigned)l << 3;

    float a[8];
#pragma unroll
    for (int k = 0; k < 8; k++) a[k] = 0.f;

    for (int e = beg; e < end; e += 16) {
        int s[8];
#pragma unroll
        for (int k = 0; k < 8; k++) {
            int ee = e + 2 * k + g;
            int idx = csr_src[min(ee, end - 1)];
            s[k] = (ee < end) ? idx : N;          // N = zero row
        }
#pragma unroll
        for (int k = 0; k < 8; k++) {
            uint2 v = *(const uint2*)(xbase + (((unsigned)s[k] << 7) + loff));
            f32x2 p0 = __builtin_amdgcn_cvt_pk_f32_fp8(v.x, false);
            f32x2 p1 = __builtin_amdgcn_cvt_pk_f32_fp8(v.x, true);
            f32x2 p2 = __builtin_amdgcn_cvt_pk_f32_fp8(v.y, false);
            f32x2 p3 = __builtin_amdgcn_cvt_pk_f32_fp8(v.y, true);
            a[0] += p0.x; a[1] += p0.y; a[2] += p1.x; a[3] += p1.y;
            a[4] += p2.x; a[5] += p2.y; a[6] += p3.x; a[7] += p3.y;
        }
    }

#pragma unroll
    for (int k = 0; k < 8; k++)
        a[k] += __shfl_xor(a[k], 16);          // combine the 2 groups
    if (g == 0 && valid) {
        float inv = 1.0f / fmaxf((float)(end - beg), 1.0f);
        unsigned int ow[4];
#pragma unroll
        for (int k = 0; k < 4; k++)
            ow[k] = (unsigned int)f2b(a[2 * k] * inv) |
                    ((unsigned int)f2b(a[2 * k + 1] * inv) << 16);
        *(uint4*)((char*)aggb + (((unsigned)node << 8) + ((unsigned)l << 4))) = *(uint4*)ow;
    }
}

// Same 2-node/16-edge-window structure over split bf16 t2. Lanes l 0-7 of a
// group read uint2 from t2lo (64B rows), 8-9 from t2hi (16B rows); l 10-15
// idle. 8 gathers/lane in flight. Zero rows at N keep the loop predicated.
__global__ void agg2_add(const unsigned short* __restrict__ t2lo,
                         const unsigned short* __restrict__ t2hi,
                         const int* __restrict__ row_start,
                         const int* __restrict__ csr_src, const float* __restrict__ b2,
                         float* __restrict__ out, int N) {
    int wv = (blockIdx.x * blockDim.x + threadIdx.x) >> 6;
    int lane = threadIdx.x & 63;
    if (2 * wv >= N) return;
    int node = 2 * wv + (lane >> 5);
    bool valid = node < N;
    int hl = lane & 31;
    int g = hl >> 4;
    int l = hl & 15;
    int beg = valid ? row_start[node] : 0;
    int end = valid ? row_start[node + 1] : 0;
    const char* lob = (const char*)t2lo;
    const char* hib = (const char*)t2hi;
    bool isLo = (l < 8);
    bool active = (l < 10);
    unsigned loff = isLo ? ((unsigned)l << 3) : ((unsigned)(l - 8) << 3);

    float a0 = 0.f, a1 = 0.f, a2 = 0.f, a3 = 0.f;

    for (int e = beg; e < end; e += 16) {
        int s[8];
#pragma unroll
        for (int k = 0; k < 8; k++) {
            int ee = e + 2 * k + g;
            int idx = csr_src[min(ee, end - 1)];
            s[k] = (ee < end) ? idx : N;          // N = zero row
        }
        if (active) {
#pragma unroll
            for (int k = 0; k < 8; k++) {
                uint2 v = isLo ? *(const uint2*)(lob + (((unsigned)s[k] << 6) + loff))
                               : *(const uint2*)(hib + (((unsigned)s[k] << 4) + loff));
                a0 += blo(v.x); a1 += bhi(v.x);
                a2 += blo(v.y); a3 += bhi(v.y);
            }
        }
    }

    a0 += __shfl_xor(a0, 16);
    a1 += __shfl_xor(a1, 16);
    a2 += __shfl_xor(a2, 16);
    a3 += __shfl_xor(a3, 16);
    if (g == 0 && active && valid) {
        float inv = 1.0f / fmaxf((float)(end - beg), 1.0f);
        float4 bb = ((const float4*)b2)[l];
        float4* op = (float4*)((char*)out + ((unsigned)node * 160u + ((unsigned)l << 4)));
        float4 cur = *op;
        cur.x += a0 * inv + bb.x;
        cur.y += a1 * inv + bb.y;
        cur.z += a2 * inv + bb.z;
        cur.w += a3 * inv + bb.w;
        *op = cur;
    }
}

// --------------------------------------------------------------- fused GEMM
// Phase 1: h1 = relu([xb|aggb] @ W1cat + b1) into LDS (128x136-stride bf16).
// Phase 2: [out_self | t2lo|t2hi] = h1_tile @ W2cat (W2t in LDS, loaded once).

__global__ __launch_bounds__(256) void gemm12_mfma(
    const unsigned short* __restrict__ xb, const unsigned short* __restrict__ aggb,
    const unsigned short* __restrict__ W1t, const unsigned short* __restrict__ W2t,
    const float* __restrict__ b1, float* __restrict__ out,
    unsigned short* __restrict__ t2lo, unsigned short* __restrict__ t2hi, int N) {

    __shared__ unsigned short As[128 * 40];
    __shared__ unsigned short Bs[128 * 40];
    __shared__ unsigned short Hs[128 * 136];   // h1 tile, +8 pad
    __shared__ unsigned short B2[80 * 136];    // W2t resident

    int tid = threadIdx.x;
    int wave = tid >> 6, lane = tid & 63;
    int row0 = blockIdx.x * 128;
    int m = lane & 15, quad = lane >> 4;

    for (int idx = tid; idx < 1280; idx += 256) {
        int r = idx >> 4, seg = idx & 15;
        *(float4*)&B2[r * 136 + seg * 8] = *(const float4*)(W2t + (size_t)r * 128 + seg * 8);
    }

    f32x4 acc[2][8];
#pragma unroll
    for (int i = 0; i < 2; i++)
#pragma unroll
        for (int j = 0; j < 8; j++) acc[i][j] = (f32x4){0.f, 0.f, 0.f, 0.f};

    for (int k0 = 0; k0 < 256; k0 += 32) {
        __syncthreads();
        {
            int r = tid >> 1, kk = (tid & 1) * 16;
            int row = row0 + r;
            float4 v0 = make_float4(0, 0, 0, 0), v1 = v0;
            if (row < N) {
                const unsigned short* s = (k0 < 128)
                    ? (xb + (size_t)row * 128 + k0 + kk)
                    : (aggb + (size_t)row * 128 + (k0 - 128) + kk);
                const float4* p = (const float4*)s;
                v0 = p[0]; v1 = p[1];
            }
            *(float4*)&As[r * 40 + kk] = v0;
            *(float4*)&As[r * 40 + kk + 8] = v1;
            const float4* q2 = (const float4*)(W1t + (size_t)r * 256 + k0 + kk);
            float4 w0 = q2[0], w1 = q2[1];
            *(float4*)&Bs[r * 40 + kk] = w0;
            *(float4*)&Bs[r * 40 + kk + 8] = w1;
        }
        __syncthreads();

        bf16x8 af0 = *(bf16x8*)&As[(wave * 32 + m) * 40 + quad * 8];
        bf16x8 af1 = *(bf16x8*)&As[(wave * 32 + 16 + m) * 40 + quad * 8];
#pragma unroll
        for (int j = 0; j < 8; j++) {
            bf16x8 bfg = *(bf16x8*)&Bs[(j * 16 + m) * 40 + quad * 8];
            acc[0][j] = __builtin_amdgcn_mfma_f32_16x16x32_bf16(af0, bfg, acc[0][j], 0, 0, 0);
            acc[1][j] = __builtin_amdgcn_mfma_f32_16x16x32_bf16(af1, bfg, acc[1][j], 0, 0, 0);
        }
    }

#pragma unroll
    for (int j = 0; j < 8; j++) {
        int col = j * 16 + m;
        float bias = b1[col];
#pragma unroll
        for (int i = 0; i < 2; i++) {
#pragma unroll
            for (int r = 0; r < 4; r++) {
                int rl = wave * 32 + i * 16 + quad * 4 + r;
                Hs[rl * 136 + col] = f2b(fmaxf(acc[i][j][r] + bias, 0.f));
            }
        }
    }
    __syncthreads();

    f32x4 acc2[2][5];
#pragma unroll
    for (int i = 0; i < 2; i++)
#pragma unroll
        for (int j = 0; j < 5; j++) acc2[i][j] = (f32x4){0.f, 0.f, 0.f, 0.f};

#pragma unroll
    for (int k0 = 0; k0 < 128; k0 += 32) {
        bf16x8 af0 = *(bf16x8*)&Hs[(wave * 32 + m) * 136 + k0 + quad * 8];
        bf16x8 af1 = *(bf16x8*)&Hs[(wave * 32 + 16 + m) * 136 + k0 + quad * 8];
#pragma unroll
        for (int j = 0; j < 5; j++) {
            bf16x8 bfg = *(bf16x8*)&B2[(j * 16 + m) * 136 + k0 + quad * 8];
            acc2[0][j] = __builtin_amdgcn_mfma_f32_16x16x32_bf16(af0, bfg, acc2[0][j], 0, 0, 0);
            acc2[1][j] = __builtin_amdgcn_mfma_f32_16x16x32_bf16(af1, bfg, acc2[1][j], 0, 0, 0);
        }
    }

#pragma unroll
    for (int j = 0; j < 5; j++) {
        int col = j * 16 + m;
#pragma unroll
        for (int i = 0; i < 2; i++) {
#pragma unroll
            for (int r = 0; r < 4; r++) {
                int row = row0 + wave * 32 + i * 16 + quad * 4 + r;
                if (row < N) {
                    float v = acc2[i][j][r];
                    if (col < 40) {
                        out[(size_t)row * 40 + col] = v;
                    } else {
                        int td = col - 40;
                        if (td < 32) t2lo[(size_t)row * 32 + td] = f2b(v);
                        else         t2hi[(size_t)row * 8 + (td - 32)] = f2b(v);
                    }
                }
            }
        }
    }
}

// ------------------------------------------------------------------ launch

extern "C" void kernel_launch(void* const* d_in, const int* in_sizes, int n_in,
                              void* d_out, int out_size, void* d_ws, size_t ws_size,
                              hipStream_t stream) {
    const float* x   = (const float*)d_in[0];
    const int*   src = (const int*)d_in[1];
    const int*   dst = (const int*)d_in[2];
    const float* W1s = (const float*)d_in[3];
    const float* W1n = (const float*)d_in[4];
    const float* b1  = (const float*)d_in[5];
    const float* W2s = (const float*)d_in[6];
    const float* W2n = (const float*)d_in[7];
    const float* b2  = (const float*)d_in[8];
    float* out = (float*)d_out;

    int N = in_sizes[0] / 128;
    int E = in_sizes[1];
    int nbins = (N + BIN_SIZE - 1) / BIN_SIZE;   // 782 for N=100000
    int M = nbins * NB;

    char* ws = (char*)d_ws;
    int*            row_start  = (int*)(ws + OFF_ROWSTART);
    int*            hist       = (int*)(ws + OFF_HIST);
    int*            scanned    = (int*)(ws + OFF_SCAN);
    int*            bsums      = (int*)(ws + OFF_BSUMS);
    int*            boffs      = (int*)(ws + OFF_BOFFS);
    unsigned int*   packed     = (unsigned int*)(ws + OFF_PACKED);
    int*            csr_src    = (int*)(ws + OFF_CSR);
    unsigned short* W1t        = (unsigned short*)(ws + OFF_W1T);
    unsigned short* W2t        = (unsigned short*)(ws + OFF_W2T);
    unsigned short* xb         = (unsigned short*)(ws + OFF_XB);
    unsigned char*  xq         = (unsigned char*)(ws + OFF_XQ);
    unsigned short* aggb       = (unsigned short*)(ws + OFF_AGGB);
    unsigned short* t2lo       = (unsigned short*)(ws + OFF_T2LO);
    unsigned short* t2hi       = (unsigned short*)(ws + OFF_T2HI);

    int scanBlocks = (M + 255) / 256;            // == nbins

    int n16 = N * 128 / 16;
    int castBlocks = (n16 + 255) / 256;
    int castPlus = castBlocks + 128 + 80 + 1;

    cast_hist<<<castPlus + NB, 256, 0, stream>>>(
        x, W1s, W1n, W2s, W2n, xb, xq, W1t, W2t, t2lo, t2hi,
        dst, hist, n16, castBlocks, castPlus, N, E, nbins);
    scan1<<<scanBlocks, 256, 0, stream>>>(hist, scanned, bsums, M);
    scan2<<<1, 1024, 0, stream>>>(bsums, boffs, scanBlocks);
    scatter_det<<<NB, 256, 0, stream>>>(src, dst, scanned, boffs, packed, E, nbins);
    bin_fill<<<nbins, 256, 0, stream>>>(packed, scanned, boffs, row_start, csr_src, N, nbins, E);

    int nodePairs = (N + 1) / 2;
    int aggBlocks = (nodePairs * 64 + 255) / 256;
    agg_mean_fp8<<<aggBlocks, 256, 0, stream>>>(xq, row_start, csr_src, aggb, N);
    gemm12_mfma<<<(N + 127) / 128, 256, 0, stream>>>(xb, aggb, W1t, W2t, b1, out, t2lo, t2hi, N);
    agg2_add<<<aggBlocks, 256, 0, stream>>>(t2lo, t2hi, row_start, csr_src, b2, out, N);
}

// Round 12
// 261.988 us; speedup vs baseline: 1.5808x; 1.0468x over previous
//
#include <hip/hip_runtime.h>

// GraphSAGE 2-layer forward on MI355X.
// Round 22: r21/r15 base (verified 273.5-274.2us) + occupancy fix for the
// CSR scatter. r21 profile surfaced scatter_det = 40.5us at Occupancy 6.9%,
// VALUBusy 1.0%: the NB=256 grid (1 block/CU, 4 waves) starves a latency-
// bound LDS-atomic + random-4B-write chain. Grid must stay 256 (block b
// owns hist column b), so threads/block 256 -> 1024 (16 waves/CU, 4x edges
// in flight). bin_fill 256 -> 512 threads (same logic; 128-wide scan is
// guarded). No ordering/data-structure change; within-bin order was already
// nondeterministic across waves (validated by every passing run).
// All other kernels byte-for-byte r21:
//   agg_mean: fp8 rows 128B, wave=2 nodes, 16-edge window, 8 uint2
//             gathers/lane in flight, zero-row predication.
//   agg2:     same structure over split bf16 t2 (t2lo 64B / t2hi 16B rows).
//   prep:     cast + W transposes + bin-histogram merged in one launch.
// CSR: deterministic counting sort. GEMM: fused gemm12 (h1 tile in LDS).

typedef __attribute__((ext_vector_type(8))) short bf16x8;
typedef __attribute__((ext_vector_type(4))) float f32x4;
typedef __attribute__((ext_vector_type(2))) float f32x2;

#define BIN_SHIFT 7
#define BIN_SIZE  128
#define NB        256          // scatter blocks (= scan block size!)

#define OFF_ROWSTART (1ull << 20)   // 400 KB
#define OFF_HIST     (2ull << 20)   // 800 KB  hist[bin*NB + blk]
#define OFF_SCAN     (3ull << 20)   // 800 KB  block-local exclusive prefix
#define OFF_BSUMS    (4ull << 20)
#define OFF_BOFFS    ((4ull << 20) + (64ull << 10))
#define OFF_PACKED   (5ull << 20)   // 6.4 MB
#define OFF_CSR      (12ull << 20)  // 6.4 MB
#define OFF_W1T      (19ull << 20)  // 64 KB
#define OFF_W2T      (20ull << 20)  // 20 KB
#define OFF_XB       (21ull << 20)  // 25.6 MB bf16 (gemm12 self-term)
#define OFF_XQ       (47ull << 20)  // 12.8 MB + zero row (fp8, N+1 rows)
#define OFF_AGGB     (61ull << 20)  // 25.6 MB bf16
#define OFF_T2LO     (87ull << 20)  // 6.4 MB + zero row (32 bf16/row)
#define OFF_T2HI     (94ull << 20)  // 1.6 MB + zero row (8 bf16/row)

static __device__ __forceinline__ unsigned short f2b(float f) {
    unsigned int u = __float_as_uint(f);
    u += 0x7fffu + ((u >> 16) & 1u);   // round-to-nearest-even
    return (unsigned short)(u >> 16);
}
static __device__ __forceinline__ float blo(unsigned int v) { return __uint_as_float(v << 16); }
static __device__ __forceinline__ float bhi(unsigned int v) { return __uint_as_float(v & 0xffff0000u); }

// --------------------------------------- merged prep: cast_prep + hist_local
// blocks [0, castBlocks): x -> xb (bf16) + xq (fp8 e4m3), 16 dims/thread.
// next 128: W1t transpose; next 80: W2t; next 1: zero rows.
// blocks [castPlus, castPlus+NB): dst histogram into hist[bin*NB + blk].

__global__ __launch_bounds__(256) void cast_hist(
    const float* __restrict__ x,
    const float* __restrict__ W1s, const float* __restrict__ W1n,
    const float* __restrict__ W2s, const float* __restrict__ W2n,
    unsigned short* __restrict__ xb, unsigned char* __restrict__ xq,
    unsigned short* __restrict__ W1t, unsigned short* __restrict__ W2t,
    unsigned short* __restrict__ t2lo, unsigned short* __restrict__ t2hi,
    const int* __restrict__ dst, int* __restrict__ hist,
    int n16, int castBlocks, int castPlus, int N, int E, int nbins) {
    __shared__ int h[1024];
    int blk = blockIdx.x, t = threadIdx.x;
    if (blk >= castPlus) {
        // ---- histogram part
        int b = blk - castPlus;
        for (int i = t; i < nbins; i += 256) h[i] = 0;
        __syncthreads();
        int chunk = (E + NB - 1) / NB;
        int base = b * chunk;
        int lim = min(base + chunk, E);
        for (int e = base + t; e < lim; e += 256)
            atomicAdd(&h[dst[e] >> BIN_SHIFT], 1);
        __syncthreads();
        for (int i = t; i < nbins; i += 256)
            hist[i * NB + b] = h[i];
        return;
    }
    if (blk < castBlocks) {
        int i = blk * 256 + t;
        if (i >= n16) return;
        const float4* p = (const float4*)x + (size_t)i * 4;
        float4 v0 = p[0], v1 = p[1], v2 = p[2], v3 = p[3];
        float f[16] = {v0.x, v0.y, v0.z, v0.w, v1.x, v1.y, v1.z, v1.w,
                       v2.x, v2.y, v2.z, v2.w, v3.x, v3.y, v3.z, v3.w};
        unsigned short ob[16];
#pragma unroll
        for (int k = 0; k < 16; k++) ob[k] = f2b(f[k]);
        *(float4*)(xb + (size_t)i * 16) = *(float4*)&ob[0];
        *(float4*)(xb + (size_t)i * 16 + 8) = *(float4*)&ob[8];
        unsigned int w[4];
#pragma unroll
        for (int k = 0; k < 4; k++) {
            int u = __builtin_amdgcn_cvt_pk_fp8_f32(f[4 * k + 0], f[4 * k + 1], 0, false);
            u = __builtin_amdgcn_cvt_pk_fp8_f32(f[4 * k + 2], f[4 * k + 3], u, true);
            w[k] = (unsigned int)u;
        }
        *(uint4*)(xq + (size_t)i * 16) = *(uint4*)w;
    } else if (blk < castBlocks + 128) {
        int c = blk - castBlocks;
        float v = (t < 128) ? W1s[(size_t)t * 128 + c] : W1n[(size_t)(t - 128) * 128 + c];
        W1t[(size_t)c * 256 + t] = f2b(v);
    } else if (blk < castBlocks + 208) {
        if (t < 128) {
            int c = blk - castBlocks - 128;
            float v = (c < 40) ? W2s[(size_t)t * 40 + c] : W2n[(size_t)t * 40 + (c - 40)];
            W2t[(size_t)c * 128 + t] = f2b(v);
        }
    } else {
        // zero rows at index N
        if (t < 32) ((unsigned int*)(xq + (size_t)N * 128))[t] = 0u;
        else if (t < 48) ((unsigned int*)(t2lo + (size_t)N * 32))[t - 32] = 0u;
        else if (t < 52) ((unsigned int*)(t2hi + (size_t)N * 8))[t - 48] = 0u;
    }
}

// ------------------------------------------------- CSR via counting sort

__global__ void scan1(const int* __restrict__ in, int* __restrict__ tmp,
                      int* __restrict__ bsums, int M) {
    __shared__ int s[256];
    int t = threadIdx.x;
    int i = blockIdx.x * 256 + t;
    int v = (i < M) ? in[i] : 0;
    s[t] = v;
    __syncthreads();
    for (int off = 1; off < 256; off <<= 1) {
        int u = (t >= off) ? s[t - off] : 0;
        __syncthreads();
        s[t] += u;
        __syncthreads();
    }
    if (i < M) tmp[i] = s[t] - v;
    if (t == 255) bsums[blockIdx.x] = s[t];
}

__global__ void scan2(const int* __restrict__ bsums, int* __restrict__ boffs, int nb) {
    __shared__ int s[1024];
    int t = threadIdx.x;
    int v = (t < nb) ? bsums[t] : 0;
    s[t] = v;
    __syncthreads();
    for (int off = 1; off < 1024; off <<= 1) {
        int u = (t >= off) ? s[t - off] : 0;
        __syncthreads();
        s[t] += u;
        __syncthreads();
    }
    if (t < nb) boffs[t] = s[t] - v;
}

// 1024 threads (16 waves): the grid is pinned to NB=256 (block b = hist
// column b), so occupancy must come from block size. 4x edges in flight on
// a latency-bound LDS-atomic + random-write chain (r21: 6.9% occ, 1% VALU).
__global__ __launch_bounds__(1024) void scatter_det(
    const int* __restrict__ src, const int* __restrict__ dst,
    const int* __restrict__ tmp, const int* __restrict__ boffs,
    unsigned int* __restrict__ packed, int E, int nbins) {
    __shared__ int cur[1024];
    int b = blockIdx.x, t = threadIdx.x;
    for (int i = t; i < nbins; i += 1024) cur[i] = tmp[i * NB + b] + boffs[i];
    __syncthreads();
    int chunk = (E + NB - 1) / NB;
    int base = b * chunk;
    int lim = min(base + chunk, E);
    for (int e = base + t; e < lim; e += 1024) {
        int d = dst[e];
        int bin = d >> BIN_SHIFT;
        int pos = atomicAdd(&cur[bin], 1);   // LDS atomic
        packed[pos] = ((unsigned int)(d & (BIN_SIZE - 1)) << 20) | (unsigned int)src[e];
    }
}

__global__ __launch_bounds__(512) void bin_fill(
    const unsigned int* __restrict__ packed, const int* __restrict__ tmp,
    const int* __restrict__ boffs,
    int* __restrict__ row_start, int* __restrict__ csr_src, int N, int nbins, int E) {
    __shared__ int cnt[BIN_SIZE];
    __shared__ int pre[BIN_SIZE];
    __shared__ int ex[BIN_SIZE];
    int b = blockIdx.x;
    int t = threadIdx.x;
    int node0 = b << BIN_SHIFT;
    int beg = tmp[b * NB] + boffs[b];
    int end = (b + 1 < nbins) ? (tmp[(b + 1) * NB] + boffs[b + 1]) : E;

    if (t < BIN_SIZE) cnt[t] = 0;
    __syncthreads();
    for (int i = beg + t; i < end; i += 512)
        atomicAdd(&cnt[packed[i] >> 20], 1);
    __syncthreads();
    if (t < BIN_SIZE) pre[t] = cnt[t];
    __syncthreads();
    for (int off = 1; off < BIN_SIZE; off <<= 1) {
        int u = (t < BIN_SIZE && t >= off) ? pre[t - off] : 0;
        __syncthreads();
        if (t < BIN_SIZE) pre[t] += u;
        __syncthreads();
    }
    if (t < BIN_SIZE) {
        ex[t] = pre[t] - cnt[t];
        int node = node0 + t;
        if (node < N) row_start[node] = beg + ex[t];
        cnt[t] = 0;
    }
    if (b == nbins - 1 && t == 0) row_start[N] = E;
    __syncthreads();
    for (int i = beg + t; i < end; i += 512) {
        unsigned int p = packed[i];
        int dl = p >> 20;
        int s = p & 0xFFFFF;
        int ofs = atomicAdd(&cnt[dl], 1);
        csr_src[beg + ex[dl] + ofs] = s;
    }
}

// ------------------------------------------------------- aggregation kernels

// Wave = 2 nodes (32-lane half each). Within a half: group g (16 lanes)
// handles edges e+2k+g, k=0..7 -> 16-edge window per node, 8 gathers/lane
// in flight. Lane-in-group l owns dims [8l, 8l+8) of the 128B fp8 row via
// uint2. Out-of-range slots clamp to zero row N. Reduce = 1 shuffle stage.
__global__ void agg_mean_fp8(const unsigned char* __restrict__ xq,
                             const int* __restrict__ row_start,
                             const int* __restrict__ csr_src,
                             unsigned short* __restrict__ aggb, int N) {
    int wv = (blockIdx.x * blockDim.x + threadIdx.x) >> 6;
    int lane = threadIdx.x & 63;
    if (2 * wv >= N) return;
    int node = 2 * wv + (lane >> 5);
    bool valid = node < N;
    int hl = lane & 31;
    int g = hl >> 4;
    int l = hl & 15;
    int beg = valid ? row_start[node] : 0;
    int end = valid ? row_start[node + 1] : 0;
    const char* xbase = (const char*)xq;
    unsigned loff = (unsigned)l << 3;

    float a[8];
#pragma unroll
    for (int k = 0; k < 8; k++) a[k] = 0.f;

    for (int e = beg; e < end; e += 16) {
        int s[8];
#pragma unroll
        for (int k = 0; k < 8; k++) {
            int ee = e + 2 * k + g;
            int idx = csr_src[min(ee, end - 1)];
            s[k] = (ee < end) ? idx : N;          // N = zero row
        }
#pragma unroll
        for (int k = 0; k < 8; k++) {
            uint2 v = *(const uint2*)(xbase + (((unsigned)s[k] << 7) + loff));
            f32x2 p0 = __builtin_amdgcn_cvt_pk_f32_fp8(v.x, false);
            f32x2 p1 = __builtin_amdgcn_cvt_pk_f32_fp8(v.x, true);
            f32x2 p2 = __builtin_amdgcn_cvt_pk_f32_fp8(v.y, false);
            f32x2 p3 = __builtin_amdgcn_cvt_pk_f32_fp8(v.y, true);
            a[0] += p0.x; a[1] += p0.y; a[2] += p1.x; a[3] += p1.y;
            a[4] += p2.x; a[5] += p2.y; a[6] += p3.x; a[7] += p3.y;
        }
    }

#pragma unroll
    for (int k = 0; k < 8; k++)
        a[k] += __shfl_xor(a[k], 16);          // combine the 2 groups
    if (g == 0 && valid) {
        float inv = 1.0f / fmaxf((float)(end - beg), 1.0f);
        unsigned int ow[4];
#pragma unroll
        for (int k = 0; k < 4; k++)
            ow[k] = (unsigned int)f2b(a[2 * k] * inv) |
                    ((unsigned int)f2b(a[2 * k + 1] * inv) << 16);
        *(uint4*)((char*)aggb + (((unsigned)node << 8) + ((unsigned)l << 4))) = *(uint4*)ow;
    }
}

// Same 2-node/16-edge-window structure over split bf16 t2. Lanes l 0-7 of a
// group read uint2 from t2lo (64B rows), 8-9 from t2hi (16B rows); l 10-15
// idle. 8 gathers/lane in flight. Zero rows at N keep the loop predicated.
__global__ void agg2_add(const unsigned short* __restrict__ t2lo,
                         const unsigned short* __restrict__ t2hi,
                         const int* __restrict__ row_start,
                         const int* __restrict__ csr_src, const float* __restrict__ b2,
                         float* __restrict__ out, int N) {
    int wv = (blockIdx.x * blockDim.x + threadIdx.x) >> 6;
    int lane = threadIdx.x & 63;
    if (2 * wv >= N) return;
    int node = 2 * wv + (lane >> 5);
    bool valid = node < N;
    int hl = lane & 31;
    int g = hl >> 4;
    int l = hl & 15;
    int beg = valid ? row_start[node] : 0;
    int end = valid ? row_start[node + 1] : 0;
    const char* lob = (const char*)t2lo;
    const char* hib = (const char*)t2hi;
    bool isLo = (l < 8);
    bool active = (l < 10);
    unsigned loff = isLo ? ((unsigned)l << 3) : ((unsigned)(l - 8) << 3);

    float a0 = 0.f, a1 = 0.f, a2 = 0.f, a3 = 0.f;

    for (int e = beg; e < end; e += 16) {
        int s[8];
#pragma unroll
        for (int k = 0; k < 8; k++) {
            int ee = e + 2 * k + g;
            int idx = csr_src[min(ee, end - 1)];
            s[k] = (ee < end) ? idx : N;          // N = zero row
        }
        if (active) {
#pragma unroll
            for (int k = 0; k < 8; k++) {
                uint2 v = isLo ? *(const uint2*)(lob + (((unsigned)s[k] << 6) + loff))
                               : *(const uint2*)(hib + (((unsigned)s[k] << 4) + loff));
                a0 += blo(v.x); a1 += bhi(v.x);
                a2 += blo(v.y); a3 += bhi(v.y);
            }
        }
    }

    a0 += __shfl_xor(a0, 16);
    a1 += __shfl_xor(a1, 16);
    a2 += __shfl_xor(a2, 16);
    a3 += __shfl_xor(a3, 16);
    if (g == 0 && active && valid) {
        float inv = 1.0f / fmaxf((float)(end - beg), 1.0f);
        float4 bb = ((const float4*)b2)[l];
        float4* op = (float4*)((char*)out + ((unsigned)node * 160u + ((unsigned)l << 4)));
        float4 cur = *op;
        cur.x += a0 * inv + bb.x;
        cur.y += a1 * inv + bb.y;
        cur.z += a2 * inv + bb.z;
        cur.w += a3 * inv + bb.w;
        *op = cur;
    }
}

// --------------------------------------------------------------- fused GEMM
// Phase 1: h1 = relu([xb|aggb] @ W1cat + b1) into LDS (128x136-stride bf16).
// Phase 2: [out_self | t2lo|t2hi] = h1_tile @ W2cat (W2t in LDS, loaded once).

__global__ __launch_bounds__(256) void gemm12_mfma(
    const unsigned short* __restrict__ xb, const unsigned short* __restrict__ aggb,
    const unsigned short* __restrict__ W1t, const unsigned short* __restrict__ W2t,
    const float* __restrict__ b1, float* __restrict__ out,
    unsigned short* __restrict__ t2lo, unsigned short* __restrict__ t2hi, int N) {

    __shared__ unsigned short As[128 * 40];
    __shared__ unsigned short Bs[128 * 40];
    __shared__ unsigned short Hs[128 * 136];   // h1 tile, +8 pad
    __shared__ unsigned short B2[80 * 136];    // W2t resident

    int tid = threadIdx.x;
    int wave = tid >> 6, lane = tid & 63;
    int row0 = blockIdx.x * 128;
    int m = lane & 15, quad = lane >> 4;

    for (int idx = tid; idx < 1280; idx += 256) {
        int r = idx >> 4, seg = idx & 15;
        *(float4*)&B2[r * 136 + seg * 8] = *(const float4*)(W2t + (size_t)r * 128 + seg * 8);
    }

    f32x4 acc[2][8];
#pragma unroll
    for (int i = 0; i < 2; i++)
#pragma unroll
        for (int j = 0; j < 8; j++) acc[i][j] = (f32x4){0.f, 0.f, 0.f, 0.f};

    for (int k0 = 0; k0 < 256; k0 += 32) {
        __syncthreads();
        {
            int r = tid >> 1, kk = (tid & 1) * 16;
            int row = row0 + r;
            float4 v0 = make_float4(0, 0, 0, 0), v1 = v0;
            if (row < N) {
                const unsigned short* s = (k0 < 128)
                    ? (xb + (size_t)row * 128 + k0 + kk)
                    : (aggb + (size_t)row * 128 + (k0 - 128) + kk);
                const float4* p = (const float4*)s;
                v0 = p[0]; v1 = p[1];
            }
            *(float4*)&As[r * 40 + kk] = v0;
            *(float4*)&As[r * 40 + kk + 8] = v1;
            const float4* q2 = (const float4*)(W1t + (size_t)r * 256 + k0 + kk);
            float4 w0 = q2[0], w1 = q2[1];
            *(float4*)&Bs[r * 40 + kk] = w0;
            *(float4*)&Bs[r * 40 + kk + 8] = w1;
        }
        __syncthreads();

        bf16x8 af0 = *(bf16x8*)&As[(wave * 32 + m) * 40 + quad * 8];
        bf16x8 af1 = *(bf16x8*)&As[(wave * 32 + 16 + m) * 40 + quad * 8];
#pragma unroll
        for (int j = 0; j < 8; j++) {
            bf16x8 bfg = *(bf16x8*)&Bs[(j * 16 + m) * 40 + quad * 8];
            acc[0][j] = __builtin_amdgcn_mfma_f32_16x16x32_bf16(af0, bfg, acc[0][j], 0, 0, 0);
            acc[1][j] = __builtin_amdgcn_mfma_f32_16x16x32_bf16(af1, bfg, acc[1][j], 0, 0, 0);
        }
    }

#pragma unroll
    for (int j = 0; j < 8; j++) {
        int col = j * 16 + m;
        float bias = b1[col];
#pragma unroll
        for (int i = 0; i < 2; i++) {
#pragma unroll
            for (int r = 0; r < 4; r++) {
                int rl = wave * 32 + i * 16 + quad * 4 + r;
                Hs[rl * 136 + col] = f2b(fmaxf(acc[i][j][r] + bias, 0.f));
            }
        }
    }
    __syncthreads();

    f32x4 acc2[2][5];
#pragma unroll
    for (int i = 0; i < 2; i++)
#pragma unroll
        for (int j = 0; j < 5; j++) acc2[i][j] = (f32x4){0.f, 0.f, 0.f, 0.f};

#pragma unroll
    for (int k0 = 0; k0 < 128; k0 += 32) {
        bf16x8 af0 = *(bf16x8*)&Hs[(wave * 32 + m) * 136 + k0 + quad * 8];
        bf16x8 af1 = *(bf16x8*)&Hs[(wave * 32 + 16 + m) * 136 + k0 + quad * 8];
#pragma unroll
        for (int j = 0; j < 5; j++) {
            bf16x8 bfg = *(bf16x8*)&B2[(j * 16 + m) * 136 + k0 + quad * 8];
            acc2[0][j] = __builtin_amdgcn_mfma_f32_16x16x32_bf16(af0, bfg, acc2[0][j], 0, 0, 0);
            acc2[1][j] = __builtin_amdgcn_mfma_f32_16x16x32_bf16(af1, bfg, acc2[1][j], 0, 0, 0);
        }
    }

#pragma unroll
    for (int j = 0; j < 5; j++) {
        int col = j * 16 + m;
#pragma unroll
        for (int i = 0; i < 2; i++) {
#pragma unroll
            for (int r = 0; r < 4; r++) {
                int row = row0 + wave * 32 + i * 16 + quad * 4 + r;
                if (row < N) {
                    float v = acc2[i][j][r];
                    if (col < 40) {
                        out[(size_t)row * 40 + col] = v;
                    } else {
                        int td = col - 40;
                        if (td < 32) t2lo[(size_t)row * 32 + td] = f2b(v);
                        else         t2hi[(size_t)row * 8 + (td - 32)] = f2b(v);
                    }
                }
            }
        }
    }
}

// ------------------------------------------------------------------ launch

extern "C" void kernel_launch(void* const* d_in, const int* in_sizes, int n_in,
                              void* d_out, int out_size, void* d_ws, size_t ws_size,
                              hipStream_t stream) {
    const float* x   = (const float*)d_in[0];
    const int*   src = (const int*)d_in[1];
    const int*   dst = (const int*)d_in[2];
    const float* W1s = (const float*)d_in[3];
    const float* W1n = (const float*)d_in[4];
    const float* b1  = (const float*)d_in[5];
    const float* W2s = (const float*)d_in[6];
    const float* W2n = (const float*)d_in[7];
    const float* b2  = (const float*)d_in[8];
    float* out = (float*)d_out;

    int N = in_sizes[0] / 128;
    int E = in_sizes[1];
    int nbins = (N + BIN_SIZE - 1) / BIN_SIZE;   // 782 for N=100000
    int M = nbins * NB;

    char* ws = (char*)d_ws;
    int*            row_start  = (int*)(ws + OFF_ROWSTART);
    int*            hist       = (int*)(ws + OFF_HIST);
    int*            scanned    = (int*)(ws + OFF_SCAN);
    int*            bsums      = (int*)(ws + OFF_BSUMS);
    int*            boffs      = (int*)(ws + OFF_BOFFS);
    unsigned int*   packed     = (unsigned int*)(ws + OFF_PACKED);
    int*            csr_src    = (int*)(ws + OFF_CSR);
    unsigned short* W1t        = (unsigned short*)(ws + OFF_W1T);
    unsigned short* W2t        = (unsigned short*)(ws + OFF_W2T);
    unsigned short* xb         = (unsigned short*)(ws + OFF_XB);
    unsigned char*  xq         = (unsigned char*)(ws + OFF_XQ);
    unsigned short* aggb       = (unsigned short*)(ws + OFF_AGGB);
    unsigned short* t2lo       = (unsigned short*)(ws + OFF_T2LO);
    unsigned short* t2hi       = (unsigned short*)(ws + OFF_T2HI);

    int scanBlocks = (M + 255) / 256;            // == nbins

    int n16 = N * 128 / 16;
    int castBlocks = (n16 + 255) / 256;
    int castPlus = castBlocks + 128 + 80 + 1;

    cast_hist<<<castPlus + NB, 256, 0, stream>>>(
        x, W1s, W1n, W2s, W2n, xb, xq, W1t, W2t, t2lo, t2hi,
        dst, hist, n16, castBlocks, castPlus, N, E, nbins);
    scan1<<<scanBlocks, 256, 0, stream>>>(hist, scanned, bsums, M);
    scan2<<<1, 1024, 0, stream>>>(bsums, boffs, scanBlocks);
    scatter_det<<<NB, 1024, 0, stream>>>(src, dst, scanned, boffs, packed, E, nbins);
    bin_fill<<<nbins, 512, 0, stream>>>(packed, scanned, boffs, row_start, csr_src, N, nbins, E);

    int nodePairs = (N + 1) / 2;
    int aggBlocks = (nodePairs * 64 + 255) / 256;
    agg_mean_fp8<<<aggBlocks, 256, 0, stream>>>(xq, row_start, csr_src, aggb, N);
    gemm12_mfma<<<(N + 127) / 128, 256, 0, stream>>>(xb, aggb, W1t, W2t, b1, out, t2lo, t2hi, N);
    agg2_add<<<aggBlocks, 256, 0, stream>>>(t2lo, t2hi, row_start, csr_src, b2, out, N);
}

// Round 13
// 259.801 us; speedup vs baseline: 1.5941x; 1.0084x over previous
//
#include <hip/hip_runtime.h>

// GraphSAGE 2-layer forward on MI355X.
// Round 23: r22 base (verified 262.0us) + register-prefetch pipeline in
// gemm12's k-loop. r22 counters: gemm12 = 47us top dispatch, MfmaUtil 6.6%,
// VALUBusy 8.6%, Occ 16.7% -> exposed-latency (staged global load chain is
// inside the barrier pair; hipcc won't pipeline across __syncthreads; only
// 2 blocks/CU at 77KB LDS to cover). Fix: issue iter k+1's xb/aggb/W1t
// loads into registers right after iter k's LDS stores -- latency covered
// by barrier+MFMA+barrier. Prologue load overlaps the B2 staging loop.
// Pure reorder, identical numerics. All other kernels byte-for-byte r22:
//   scatter_det 1024 thr / bin_fill 512 thr (r22 occupancy fix, +12us).
//   agg_mean / agg2: wave=2 nodes, 16-edge window, 8 uint2 gathers/lane.
//   prep: cast + W transposes + bin-histogram merged.
// CSR: deterministic counting sort. GEMM: fused gemm12 (h1 tile in LDS).

typedef __attribute__((ext_vector_type(8))) short bf16x8;
typedef __attribute__((ext_vector_type(4))) float f32x4;
typedef __attribute__((ext_vector_type(2))) float f32x2;

#define BIN_SHIFT 7
#define BIN_SIZE  128
#define NB        256          // scatter blocks (= scan block size!)

#define OFF_ROWSTART (1ull << 20)   // 400 KB
#define OFF_HIST     (2ull << 20)   // 800 KB  hist[bin*NB + blk]
#define OFF_SCAN     (3ull << 20)   // 800 KB  block-local exclusive prefix
#define OFF_BSUMS    (4ull << 20)
#define OFF_BOFFS    ((4ull << 20) + (64ull << 10))
#define OFF_PACKED   (5ull << 20)   // 6.4 MB
#define OFF_CSR      (12ull << 20)  // 6.4 MB
#define OFF_W1T      (19ull << 20)  // 64 KB
#define OFF_W2T      (20ull << 20)  // 20 KB
#define OFF_XB       (21ull << 20)  // 25.6 MB bf16 (gemm12 self-term)
#define OFF_XQ       (47ull << 20)  // 12.8 MB + zero row (fp8, N+1 rows)
#define OFF_AGGB     (61ull << 20)  // 25.6 MB bf16
#define OFF_T2LO     (87ull << 20)  // 6.4 MB + zero row (32 bf16/row)
#define OFF_T2HI     (94ull << 20)  // 1.6 MB + zero row (8 bf16/row)

static __device__ __forceinline__ unsigned short f2b(float f) {
    unsigned int u = __float_as_uint(f);
    u += 0x7fffu + ((u >> 16) & 1u);   // round-to-nearest-even
    return (unsigned short)(u >> 16);
}
static __device__ __forceinline__ float blo(unsigned int v) { return __uint_as_float(v << 16); }
static __device__ __forceinline__ float bhi(unsigned int v) { return __uint_as_float(v & 0xffff0000u); }

// --------------------------------------- merged prep: cast_prep + hist_local
// blocks [0, castBlocks): x -> xb (bf16) + xq (fp8 e4m3), 16 dims/thread.
// next 128: W1t transpose; next 80: W2t; next 1: zero rows.
// blocks [castPlus, castPlus+NB): dst histogram into hist[bin*NB + blk].

__global__ __launch_bounds__(256) void cast_hist(
    const float* __restrict__ x,
    const float* __restrict__ W1s, const float* __restrict__ W1n,
    const float* __restrict__ W2s, const float* __restrict__ W2n,
    unsigned short* __restrict__ xb, unsigned char* __restrict__ xq,
    unsigned short* __restrict__ W1t, unsigned short* __restrict__ W2t,
    unsigned short* __restrict__ t2lo, unsigned short* __restrict__ t2hi,
    const int* __restrict__ dst, int* __restrict__ hist,
    int n16, int castBlocks, int castPlus, int N, int E, int nbins) {
    __shared__ int h[1024];
    int blk = blockIdx.x, t = threadIdx.x;
    if (blk >= castPlus) {
        // ---- histogram part
        int b = blk - castPlus;
        for (int i = t; i < nbins; i += 256) h[i] = 0;
        __syncthreads();
        int chunk = (E + NB - 1) / NB;
        int base = b * chunk;
        int lim = min(base + chunk, E);
        for (int e = base + t; e < lim; e += 256)
            atomicAdd(&h[dst[e] >> BIN_SHIFT], 1);
        __syncthreads();
        for (int i = t; i < nbins; i += 256)
            hist[i * NB + b] = h[i];
        return;
    }
    if (blk < castBlocks) {
        int i = blk * 256 + t;
        if (i >= n16) return;
        const float4* p = (const float4*)x + (size_t)i * 4;
        float4 v0 = p[0], v1 = p[1], v2 = p[2], v3 = p[3];
        float f[16] = {v0.x, v0.y, v0.z, v0.w, v1.x, v1.y, v1.z, v1.w,
                       v2.x, v2.y, v2.z, v2.w, v3.x, v3.y, v3.z, v3.w};
        unsigned short ob[16];
#pragma unroll
        for (int k = 0; k < 16; k++) ob[k] = f2b(f[k]);
        *(float4*)(xb + (size_t)i * 16) = *(float4*)&ob[0];
        *(float4*)(xb + (size_t)i * 16 + 8) = *(float4*)&ob[8];
        unsigned int w[4];
#pragma unroll
        for (int k = 0; k < 4; k++) {
            int u = __builtin_amdgcn_cvt_pk_fp8_f32(f[4 * k + 0], f[4 * k + 1], 0, false);
            u = __builtin_amdgcn_cvt_pk_fp8_f32(f[4 * k + 2], f[4 * k + 3], u, true);
            w[k] = (unsigned int)u;
        }
        *(uint4*)(xq + (size_t)i * 16) = *(uint4*)w;
    } else if (blk < castBlocks + 128) {
        int c = blk - castBlocks;
        float v = (t < 128) ? W1s[(size_t)t * 128 + c] : W1n[(size_t)(t - 128) * 128 + c];
        W1t[(size_t)c * 256 + t] = f2b(v);
    } else if (blk < castBlocks + 208) {
        if (t < 128) {
            int c = blk - castBlocks - 128;
            float v = (c < 40) ? W2s[(size_t)t * 40 + c] : W2n[(size_t)t * 40 + (c - 40)];
            W2t[(size_t)c * 128 + t] = f2b(v);
        }
    } else {
        // zero rows at index N
        if (t < 32) ((unsigned int*)(xq + (size_t)N * 128))[t] = 0u;
        else if (t < 48) ((unsigned int*)(t2lo + (size_t)N * 32))[t - 32] = 0u;
        else if (t < 52) ((unsigned int*)(t2hi + (size_t)N * 8))[t - 48] = 0u;
    }
}

// ------------------------------------------------- CSR via counting sort

__global__ void scan1(const int* __restrict__ in, int* __restrict__ tmp,
                      int* __restrict__ bsums, int M) {
    __shared__ int s[256];
    int t = threadIdx.x;
    int i = blockIdx.x * 256 + t;
    int v = (i < M) ? in[i] : 0;
    s[t] = v;
    __syncthreads();
    for (int off = 1; off < 256; off <<= 1) {
        int u = (t >= off) ? s[t - off] : 0;
        __syncthreads();
        s[t] += u;
        __syncthreads();
    }
    if (i < M) tmp[i] = s[t] - v;
    if (t == 255) bsums[blockIdx.x] = s[t];
}

__global__ void scan2(const int* __restrict__ bsums, int* __restrict__ boffs, int nb) {
    __shared__ int s[1024];
    int t = threadIdx.x;
    int v = (t < nb) ? bsums[t] : 0;
    s[t] = v;
    __syncthreads();
    for (int off = 1; off < 1024; off <<= 1) {
        int u = (t >= off) ? s[t - off] : 0;
        __syncthreads();
        s[t] += u;
        __syncthreads();
    }
    if (t < nb) boffs[t] = s[t] - v;
}

// 1024 threads (16 waves): the grid is pinned to NB=256 (block b = hist
// column b), so occupancy must come from block size (r22: 40.9 -> faster).
__global__ __launch_bounds__(1024) void scatter_det(
    const int* __restrict__ src, const int* __restrict__ dst,
    const int* __restrict__ tmp, const int* __restrict__ boffs,
    unsigned int* __restrict__ packed, int E, int nbins) {
    __shared__ int cur[1024];
    int b = blockIdx.x, t = threadIdx.x;
    for (int i = t; i < nbins; i += 1024) cur[i] = tmp[i * NB + b] + boffs[i];
    __syncthreads();
    int chunk = (E + NB - 1) / NB;
    int base = b * chunk;
    int lim = min(base + chunk, E);
    for (int e = base + t; e < lim; e += 1024) {
        int d = dst[e];
        int bin = d >> BIN_SHIFT;
        int pos = atomicAdd(&cur[bin], 1);   // LDS atomic
        packed[pos] = ((unsigned int)(d & (BIN_SIZE - 1)) << 20) | (unsigned int)src[e];
    }
}

__global__ __launch_bounds__(512) void bin_fill(
    const unsigned int* __restrict__ packed, const int* __restrict__ tmp,
    const int* __restrict__ boffs,
    int* __restrict__ row_start, int* __restrict__ csr_src, int N, int nbins, int E) {
    __shared__ int cnt[BIN_SIZE];
    __shared__ int pre[BIN_SIZE];
    __shared__ int ex[BIN_SIZE];
    int b = blockIdx.x;
    int t = threadIdx.x;
    int node0 = b << BIN_SHIFT;
    int beg = tmp[b * NB] + boffs[b];
    int end = (b + 1 < nbins) ? (tmp[(b + 1) * NB] + boffs[b + 1]) : E;

    if (t < BIN_SIZE) cnt[t] = 0;
    __syncthreads();
    for (int i = beg + t; i < end; i += 512)
        atomicAdd(&cnt[packed[i] >> 20], 1);
    __syncthreads();
    if (t < BIN_SIZE) pre[t] = cnt[t];
    __syncthreads();
    for (int off = 1; off < BIN_SIZE; off <<= 1) {
        int u = (t < BIN_SIZE && t >= off) ? pre[t - off] : 0;
        __syncthreads();
        if (t < BIN_SIZE) pre[t] += u;
        __syncthreads();
    }
    if (t < BIN_SIZE) {
        ex[t] = pre[t] - cnt[t];
        int node = node0 + t;
        if (node < N) row_start[node] = beg + ex[t];
        cnt[t] = 0;
    }
    if (b == nbins - 1 && t == 0) row_start[N] = E;
    __syncthreads();
    for (int i = beg + t; i < end; i += 512) {
        unsigned int p = packed[i];
        int dl = p >> 20;
        int s = p & 0xFFFFF;
        int ofs = atomicAdd(&cnt[dl], 1);
        csr_src[beg + ex[dl] + ofs] = s;
    }
}

// ------------------------------------------------------- aggregation kernels

// Wave = 2 nodes (32-lane half each). Within a half: group g (16 lanes)
// handles edges e+2k+g, k=0..7 -> 16-edge window per node, 8 gathers/lane
// in flight. Lane-in-group l owns dims [8l, 8l+8) of the 128B fp8 row via
// uint2. Out-of-range slots clamp to zero row N. Reduce = 1 shuffle stage.
__global__ void agg_mean_fp8(const unsigned char* __restrict__ xq,
                             const int* __restrict__ row_start,
                             const int* __restrict__ csr_src,
                             unsigned short* __restrict__ aggb, int N) {
    int wv = (blockIdx.x * blockDim.x + threadIdx.x) >> 6;
    int lane = threadIdx.x & 63;
    if (2 * wv >= N) return;
    int node = 2 * wv + (lane >> 5);
    bool valid = node < N;
    int hl = lane & 31;
    int g = hl >> 4;
    int l = hl & 15;
    int beg = valid ? row_start[node] : 0;
    int end = valid ? row_start[node + 1] : 0;
    const char* xbase = (const char*)xq;
    unsigned loff = (unsigned)l << 3;

    float a[8];
#pragma unroll
    for (int k = 0; k < 8; k++) a[k] = 0.f;

    for (int e = beg; e < end; e += 16) {
        int s[8];
#pragma unroll
        for (int k = 0; k < 8; k++) {
            int ee = e + 2 * k + g;
            int idx = csr_src[min(ee, end - 1)];
            s[k] = (ee < end) ? idx : N;          // N = zero row
        }
#pragma unroll
        for (int k = 0; k < 8; k++) {
            uint2 v = *(const uint2*)(xbase + (((unsigned)s[k] << 7) + loff));
            f32x2 p0 = __builtin_amdgcn_cvt_pk_f32_fp8(v.x, false);
            f32x2 p1 = __builtin_amdgcn_cvt_pk_f32_fp8(v.x, true);
            f32x2 p2 = __builtin_amdgcn_cvt_pk_f32_fp8(v.y, false);
            f32x2 p3 = __builtin_amdgcn_cvt_pk_f32_fp8(v.y, true);
            a[0] += p0.x; a[1] += p0.y; a[2] += p1.x; a[3] += p1.y;
            a[4] += p2.x; a[5] += p2.y; a[6] += p3.x; a[7] += p3.y;
        }
    }

#pragma unroll
    for (int k = 0; k < 8; k++)
        a[k] += __shfl_xor(a[k], 16);          // combine the 2 groups
    if (g == 0 && valid) {
        float inv = 1.0f / fmaxf((float)(end - beg), 1.0f);
        unsigned int ow[4];
#pragma unroll
        for (int k = 0; k < 4; k++)
            ow[k] = (unsigned int)f2b(a[2 * k] * inv) |
                    ((unsigned int)f2b(a[2 * k + 1] * inv) << 16);
        *(uint4*)((char*)aggb + (((unsigned)node << 8) + ((unsigned)l << 4))) = *(uint4*)ow;
    }
}

// Same 2-node/16-edge-window structure over split bf16 t2. Lanes l 0-7 of a
// group read uint2 from t2lo (64B rows), 8-9 from t2hi (16B rows); l 10-15
// idle. 8 gathers/lane in flight. Zero rows at N keep the loop predicated.
__global__ void agg2_add(const unsigned short* __restrict__ t2lo,
                         const unsigned short* __restrict__ t2hi,
                         const int* __restrict__ row_start,
                         const int* __restrict__ csr_src, const float* __restrict__ b2,
                         float* __restrict__ out, int N) {
    int wv = (blockIdx.x * blockDim.x + threadIdx.x) >> 6;
    int lane = threadIdx.x & 63;
    if (2 * wv >= N) return;
    int node = 2 * wv + (lane >> 5);
    bool valid = node < N;
    int hl = lane & 31;
    int g = hl >> 4;
    int l = hl & 15;
    int beg = valid ? row_start[node] : 0;
    int end = valid ? row_start[node + 1] : 0;
    const char* lob = (const char*)t2lo;
    const char* hib = (const char*)t2hi;
    bool isLo = (l < 8);
    bool active = (l < 10);
    unsigned loff = isLo ? ((unsigned)l << 3) : ((unsigned)(l - 8) << 3);

    float a0 = 0.f, a1 = 0.f, a2 = 0.f, a3 = 0.f;

    for (int e = beg; e < end; e += 16) {
        int s[8];
#pragma unroll
        for (int k = 0; k < 8; k++) {
            int ee = e + 2 * k + g;
            int idx = csr_src[min(ee, end - 1)];
            s[k] = (ee < end) ? idx : N;          // N = zero row
        }
        if (active) {
#pragma unroll
            for (int k = 0; k < 8; k++) {
                uint2 v = isLo ? *(const uint2*)(lob + (((unsigned)s[k] << 6) + loff))
                               : *(const uint2*)(hib + (((unsigned)s[k] << 4) + loff));
                a0 += blo(v.x); a1 += bhi(v.x);
                a2 += blo(v.y); a3 += bhi(v.y);
            }
        }
    }

    a0 += __shfl_xor(a0, 16);
    a1 += __shfl_xor(a1, 16);
    a2 += __shfl_xor(a2, 16);
    a3 += __shfl_xor(a3, 16);
    if (g == 0 && active && valid) {
        float inv = 1.0f / fmaxf((float)(end - beg), 1.0f);
        float4 bb = ((const float4*)b2)[l];
        float4* op = (float4*)((char*)out + ((unsigned)node * 160u + ((unsigned)l << 4)));
        float4 cur = *op;
        cur.x += a0 * inv + bb.x;
        cur.y += a1 * inv + bb.y;
        cur.z += a2 * inv + bb.z;
        cur.w += a3 * inv + bb.w;
        *op = cur;
    }
}

// --------------------------------------------------------------- fused GEMM
// Phase 1: h1 = relu([xb|aggb] @ W1cat + b1) into LDS (128x136-stride bf16).
//          k-loop is register-prefetch pipelined: iter k+1's global loads
//          issue right after iter k's LDS stores (latency covered by
//          barrier + 16 MFMAs + barrier). Prologue load overlaps B2 staging.
// Phase 2: [out_self | t2lo|t2hi] = h1_tile @ W2cat (W2t in LDS, loaded once).

__global__ __launch_bounds__(256) void gemm12_mfma(
    const unsigned short* __restrict__ xb, const unsigned short* __restrict__ aggb,
    const unsigned short* __restrict__ W1t, const unsigned short* __restrict__ W2t,
    const float* __restrict__ b1, float* __restrict__ out,
    unsigned short* __restrict__ t2lo, unsigned short* __restrict__ t2hi, int N) {

    __shared__ unsigned short As[128 * 40];
    __shared__ unsigned short Bs[128 * 40];
    __shared__ unsigned short Hs[128 * 136];   // h1 tile, +8 pad
    __shared__ unsigned short B2[80 * 136];    // W2t resident

    int tid = threadIdx.x;
    int wave = tid >> 6, lane = tid & 63;
    int row0 = blockIdx.x * 128;
    int m = lane & 15, quad = lane >> 4;

    // staging geometry (fixed per thread)
    int r = tid >> 1, kk = (tid & 1) * 16;
    int srow = row0 + r;
    bool rowOK = srow < N;

    // prologue prefetch for k0 = 0 (issues before B2 staging loads)
    float4 pa0 = make_float4(0, 0, 0, 0), pa1 = pa0, pw0, pw1;
    if (rowOK) {
        const float4* p = (const float4*)(xb + (size_t)srow * 128 + kk);
        pa0 = p[0]; pa1 = p[1];
    }
    {
        const float4* q2 = (const float4*)(W1t + (size_t)r * 256 + kk);
        pw0 = q2[0]; pw1 = q2[1];
    }

    for (int idx = tid; idx < 1280; idx += 256) {
        int rr = idx >> 4, seg = idx & 15;
        *(float4*)&B2[rr * 136 + seg * 8] = *(const float4*)(W2t + (size_t)rr * 128 + seg * 8);
    }

    f32x4 acc[2][8];
#pragma unroll
    for (int i = 0; i < 2; i++)
#pragma unroll
        for (int j = 0; j < 8; j++) acc[i][j] = (f32x4){0.f, 0.f, 0.f, 0.f};

    for (int k0 = 0; k0 < 256; k0 += 32) {
        __syncthreads();                       // prior iter's LDS reads done
        *(float4*)&As[r * 40 + kk] = pa0;      // waits on prefetched loads
        *(float4*)&As[r * 40 + kk + 8] = pa1;
        *(float4*)&Bs[r * 40 + kk] = pw0;
        *(float4*)&Bs[r * 40 + kk + 8] = pw1;
        int kn = k0 + 32;
        if (kn < 256) {                        // issue next iter's loads
            float4 na0 = make_float4(0, 0, 0, 0), na1 = na0;
            if (rowOK) {
                const unsigned short* s = (kn < 128)
                    ? (xb + (size_t)srow * 128 + kn + kk)
                    : (aggb + (size_t)srow * 128 + (kn - 128) + kk);
                const float4* p = (const float4*)s;
                na0 = p[0]; na1 = p[1];
            }
            const float4* q2 = (const float4*)(W1t + (size_t)r * 256 + kn + kk);
            pw0 = q2[0]; pw1 = q2[1];
            pa0 = na0; pa1 = na1;
        }
        __syncthreads();

        bf16x8 af0 = *(bf16x8*)&As[(wave * 32 + m) * 40 + quad * 8];
        bf16x8 af1 = *(bf16x8*)&As[(wave * 32 + 16 + m) * 40 + quad * 8];
#pragma unroll
        for (int j = 0; j < 8; j++) {
            bf16x8 bfg = *(bf16x8*)&Bs[(j * 16 + m) * 40 + quad * 8];
            acc[0][j] = __builtin_amdgcn_mfma_f32_16x16x32_bf16(af0, bfg, acc[0][j], 0, 0, 0);
            acc[1][j] = __builtin_amdgcn_mfma_f32_16x16x32_bf16(af1, bfg, acc[1][j], 0, 0, 0);
        }
    }

#pragma unroll
    for (int j = 0; j < 8; j++) {
        int col = j * 16 + m;
        float bias = b1[col];
#pragma unroll
        for (int i = 0; i < 2; i++) {
#pragma unroll
            for (int rr = 0; rr < 4; rr++) {
                int rl = wave * 32 + i * 16 + quad * 4 + rr;
                Hs[rl * 136 + col] = f2b(fmaxf(acc[i][j][rr] + bias, 0.f));
            }
        }
    }
    __syncthreads();

    f32x4 acc2[2][5];
#pragma unroll
    for (int i = 0; i < 2; i++)
#pragma unroll
        for (int j = 0; j < 5; j++) acc2[i][j] = (f32x4){0.f, 0.f, 0.f, 0.f};

#pragma unroll
    for (int k0 = 0; k0 < 128; k0 += 32) {
        bf16x8 af0 = *(bf16x8*)&Hs[(wave * 32 + m) * 136 + k0 + quad * 8];
        bf16x8 af1 = *(bf16x8*)&Hs[(wave * 32 + 16 + m) * 136 + k0 + quad * 8];
#pragma unroll
        for (int j = 0; j < 5; j++) {
            bf16x8 bfg = *(bf16x8*)&B2[(j * 16 + m) * 136 + k0 + quad * 8];
            acc2[0][j] = __builtin_amdgcn_mfma_f32_16x16x32_bf16(af0, bfg, acc2[0][j], 0, 0, 0);
            acc2[1][j] = __builtin_amdgcn_mfma_f32_16x16x32_bf16(af1, bfg, acc2[1][j], 0, 0, 0);
        }
    }

#pragma unroll
    for (int j = 0; j < 5; j++) {
        int col = j * 16 + m;
#pragma unroll
        for (int i = 0; i < 2; i++) {
#pragma unroll
            for (int rr = 0; rr < 4; rr++) {
                int row = row0 + wave * 32 + i * 16 + quad * 4 + rr;
                if (row < N) {
                    float v = acc2[i][j][rr];
                    if (col < 40) {
                        out[(size_t)row * 40 + col] = v;
                    } else {
                        int td = col - 40;
                        if (td < 32) t2lo[(size_t)row * 32 + td] = f2b(v);
                        else         t2hi[(size_t)row * 8 + (td - 32)] = f2b(v);
                    }
                }
            }
        }
    }
}

// ------------------------------------------------------------------ launch

extern "C" void kernel_launch(void* const* d_in, const int* in_sizes, int n_in,
                              void* d_out, int out_size, void* d_ws, size_t ws_size,
                              hipStream_t stream) {
    const float* x   = (const float*)d_in[0];
    const int*   src = (const int*)d_in[1];
    const int*   dst = (const int*)d_in[2];
    const float* W1s = (const float*)d_in[3];
    const float* W1n = (const float*)d_in[4];
    const float* b1  = (const float*)d_in[5];
    const float* W2s = (const float*)d_in[6];
    const float* W2n = (const float*)d_in[7];
    const float* b2  = (const float*)d_in[8];
    float* out = (float*)d_out;

    int N = in_sizes[0] / 128;
    int E = in_sizes[1];
    int nbins = (N + BIN_SIZE - 1) / BIN_SIZE;   // 782 for N=100000
    int M = nbins * NB;

    char* ws = (char*)d_ws;
    int*            row_start  = (int*)(ws + OFF_ROWSTART);
    int*            hist       = (int*)(ws + OFF_HIST);
    int*            scanned    = (int*)(ws + OFF_SCAN);
    int*            bsums      = (int*)(ws + OFF_BSUMS);
    int*            boffs      = (int*)(ws + OFF_BOFFS);
    unsigned int*   packed     = (unsigned int*)(ws + OFF_PACKED);
    int*            csr_src    = (int*)(ws + OFF_CSR);
    unsigned short* W1t        = (unsigned short*)(ws + OFF_W1T);
    unsigned short* W2t        = (unsigned short*)(ws + OFF_W2T);
    unsigned short* xb         = (unsigned short*)(ws + OFF_XB);
    unsigned char*  xq         = (unsigned char*)(ws + OFF_XQ);
    unsigned short* aggb       = (unsigned short*)(ws + OFF_AGGB);
    unsigned short* t2lo       = (unsigned short*)(ws + OFF_T2LO);
    unsigned short* t2hi       = (unsigned short*)(ws + OFF_T2HI);

    int scanBlocks = (M + 255) / 256;            // == nbins

    int n16 = N * 128 / 16;
    int castBlocks = (n16 + 255) / 256;
    int castPlus = castBlocks + 128 + 80 + 1;

    cast_hist<<<castPlus + NB, 256, 0, stream>>>(
        x, W1s, W1n, W2s, W2n, xb, xq, W1t, W2t, t2lo, t2hi,
        dst, hist, n16, castBlocks, castPlus, N, E, nbins);
    scan1<<<scanBlocks, 256, 0, stream>>>(hist, scanned, bsums, M);
    scan2<<<1, 1024, 0, stream>>>(bsums, boffs, scanBlocks);
    scatter_det<<<NB, 1024, 0, stream>>>(src, dst, scanned, boffs, packed, E, nbins);
    bin_fill<<<nbins, 512, 0, stream>>>(packed, scanned, boffs, row_start, csr_src, N, nbins, E);

    int nodePairs = (N + 1) / 2;
    int aggBlocks = (nodePairs * 64 + 255) / 256;
    agg_mean_fp8<<<aggBlocks, 256, 0, stream>>>(xq, row_start, csr_src, aggb, N);
    gemm12_mfma<<<(N + 127) / 128, 256, 0, stream>>>(xb, aggb, W1t, W2t, b1, out, t2lo, t2hi, N);
    agg2_add<<<aggBlocks, 256, 0, stream>>>(t2lo, t2hi, row_start, csr_src, b2, out, N);
}